// Round 17
// baseline (214.076 us; speedup 1.0000x reference)
//
#include <hip/hip_runtime.h>
#include <math.h>

#define B_  4
#define S_  2048
#define H_  768
#define NH_ 12
#define HD_ 64
#define M_  (B_*S_)   // 8192
#define K_  768
#define LOG2E 1.44269504088896340736f

using bf16x8 = __attribute__((ext_vector_type(8))) short;
using s16x4  = __attribute__((ext_vector_type(4))) short;
using f32x4  = __attribute__((ext_vector_type(4))) float;

__device__ inline short f2bf(float f) {
    union { float f; unsigned u; } v{f};
    unsigned r = (v.u + 0x7FFF + ((v.u >> 16) & 1)) >> 16;   // RNE
    return (short)r;
}

__device__ inline unsigned cvt_pk_bf16(float lo, float hi) {
    unsigned r;
    asm("v_cvt_pk_bf16_f32 %0, %1, %2" : "=v"(r) : "v"(lo), "v"(hi));
    return r;
}

#define GLDS16(g, l) __builtin_amdgcn_global_load_lds( \
    (const __attribute__((address_space(1))) void*)(g), \
    (__attribute__((address_space(3))) void*)(l), 16, 0, 0)

// swizzled LDS read: linear [R][128B] tile, byte ^= ((row&7)<<4)
__device__ inline const bf16x8* LDSRD(const short* base, int row, int colByte) {
    return (const bf16x8*)((const char*)base + ((row << 7) + (colByte ^ ((row & 7) << 4))));
}

// ---------------------------------------------------------------------------
// fp32 -> bf16 conversion (regions 0-4: hs, Wq, Wk, Wv, Wo) + mask*log2e (5)
// ---------------------------------------------------------------------------
__global__ __launch_bounds__(256)
void cvt6(const float* __restrict__ s0, const float* __restrict__ s1,
          const float* __restrict__ s2, const float* __restrict__ s3,
          const float* __restrict__ s4, const float* __restrict__ msk,
          short* __restrict__ d0, short* __restrict__ d1,
          short* __restrict__ d2, short* __restrict__ d3,
          short* __restrict__ d4, float* __restrict__ msk2) {
    const int r = blockIdx.y;
    if (r == 5) {
        for (int i = blockIdx.x * blockDim.x + threadIdx.x; i < (B_ * S_) / 4;
             i += gridDim.x * blockDim.x) {
            float4 v = ((const float4*)msk)[i];
            v.x *= LOG2E; v.y *= LOG2E; v.z *= LOG2E; v.w *= LOG2E;
            ((float4*)msk2)[i] = v;
        }
        return;
    }
    const float* s = r == 0 ? s0 : r == 1 ? s1 : r == 2 ? s2 : r == 3 ? s3 : s4;
    short* d      = r == 0 ? d0 : r == 1 ? d1 : r == 2 ? d2 : r == 3 ? d3 : d4;
    const int n4  = (r == 0 ? M_ * H_ : H_ * H_) >> 2;
    for (int i = blockIdx.x * blockDim.x + threadIdx.x; i < n4; i += gridDim.x * blockDim.x) {
        float4 v = ((const float4*)s)[i];
        s16x4 o;
        o[0] = f2bf(v.x); o[1] = f2bf(v.y); o[2] = f2bf(v.z); o[3] = f2bf(v.w);
        ((s16x4*)d)[i] = o;
    }
}

// ---------------------------------------------------------------------------
// Fused QKV GEMM, XCD-chunked 1-D grid (1152 blocks).
// Q/K -> bf16 head-major [b][h][s][d]; V -> transposed [b][h][d][s].
// ---------------------------------------------------------------------------
__global__ __launch_bounds__(256)
void gemm_qkv(const short* __restrict__ A, const short* __restrict__ Bw,
              const float* __restrict__ bq, const float* __restrict__ bk,
              const float* __restrict__ bv, short* __restrict__ obase,
              short* __restrict__ vt) {
    __shared__ __align__(16) short As[128 * 32];
    __shared__ __align__(16) short Bs[128 * 32];
    const int tid = threadIdx.x;
    const int w = tid >> 6, l = tid & 63;
    const int l16 = l & 15, lg = l >> 4;
    const int wm = w >> 1, wn = w & 1;
    const int flat = blockIdx.x;
    const int j = flat >> 3;
    const int mt = (flat & 7) * 8 + (j & 7);
    const int nty = j >> 3;                    // 0..17
    const int m0 = mt * 128, n0 = nty * 128;
    const int which = nty / 6;
    const float* bias = which == 0 ? bq : which == 1 ? bk : bv;
    const float scale = which == 0 ? 0.125f * LOG2E : 1.0f;

    f32x4 acc[4][4];
    #pragma unroll
    for (int mi = 0; mi < 4; mi++)
        #pragma unroll
        for (int ni = 0; ni < 4; ni++)
            acc[mi][ni][0] = acc[mi][ni][1] = acc[mi][ni][2] = acc[mi][ni][3] = 0.f;

    for (int k0 = 0; k0 < K_; k0 += 32) {
        #pragma unroll
        for (int i = 0; i < 2; i++) {
            const int o = w * 2048 + i * 1024 + l * 16;
            const int row = o >> 6, colb = o & 63;
            const char* ga = (const char*)A  + (((size_t)(m0 + row)) * K_ + k0) * 2 + colb;
            const char* gb = (const char*)Bw + (((size_t)(n0 + row)) * K_ + k0) * 2 + colb;
            GLDS16(ga, (char*)As + w * 2048 + i * 1024);
            GLDS16(gb, (char*)Bs + w * 2048 + i * 1024);
        }
        __syncthreads();

        bf16x8 af[4], bfr[4];
        #pragma unroll
        for (int mi = 0; mi < 4; mi++)
            af[mi] = *(const bf16x8*)&As[(wm * 64 + mi * 16 + l16) * 32 + lg * 8];
        #pragma unroll
        for (int ni = 0; ni < 4; ni++)
            bfr[ni] = *(const bf16x8*)&Bs[(wn * 64 + ni * 16 + l16) * 32 + lg * 8];
        #pragma unroll
        for (int mi = 0; mi < 4; mi++)
            #pragma unroll
            for (int ni = 0; ni < 4; ni++)
                acc[mi][ni] = __builtin_amdgcn_mfma_f32_16x16x32_bf16(af[mi], bfr[ni], acc[mi][ni], 0, 0, 0);
        __syncthreads();
    }

    const int ncol0 = (nty % 6) * 128;
    float bcol[4];
    #pragma unroll
    for (int ni = 0; ni < 4; ni++) bcol[ni] = bias[ncol0 + wn * 64 + ni * 16 + l16];

    const int h = (nty % 6) * 2 + wn;   // wave's 64-col span == one head
    if (which < 2) {
        short* obf = obase + (size_t)which * M_ * H_;
        #pragma unroll
        for (int mi = 0; mi < 4; mi++) {
            #pragma unroll
            for (int r = 0; r < 4; r++) {
                const int row = m0 + wm * 64 + mi * 16 + lg * 4 + r;
                const int bb = row >> 11, ss = row & 2047;
                const size_t base = (((size_t)(bb * NH_ + h)) * S_ + ss) * HD_;
                #pragma unroll
                for (int ni = 0; ni < 4; ni++)
                    obf[base + ni * 16 + l16] = f2bf((acc[mi][ni][r] + bcol[ni]) * scale);
            }
        }
    } else {
        // V: transposed store [b][h][d][s]
        #pragma unroll
        for (int mi = 0; mi < 4; mi++) {
            const int row0 = m0 + wm * 64 + mi * 16 + lg * 4;
            const int bb = row0 >> 11, ss0 = row0 & 2047;
            #pragma unroll
            for (int ni = 0; ni < 4; ni++) {
                s16x4 pk;
                pk[0] = f2bf(acc[mi][ni][0] + bcol[ni]);
                pk[1] = f2bf(acc[mi][ni][1] + bcol[ni]);
                pk[2] = f2bf(acc[mi][ni][2] + bcol[ni]);
                pk[3] = f2bf(acc[mi][ni][3] + bcol[ni]);
                *(s16x4*)(vt + (((size_t)(bb * NH_ + h)) * HD_ + ni * 16 + l16) * S_ + ss0) = pk;
            }
        }
    }
}

// ---------------------------------------------------------------------------
// O-proj GEMM, XCD-chunked 1-D grid (384 blocks).
// ---------------------------------------------------------------------------
__global__ __launch_bounds__(256)
void gemm_out(const short* __restrict__ A, const short* __restrict__ Bw,
              const float* __restrict__ bias, const float* __restrict__ res,
              float* __restrict__ o) {
    __shared__ __align__(16) short As[128 * 32];
    __shared__ __align__(16) short Bs[128 * 32];
    const int tid = threadIdx.x;
    const int w = tid >> 6, l = tid & 63;
    const int l16 = l & 15, lg = l >> 4;
    const int wm = w >> 1, wn = w & 1;
    const int flat = blockIdx.x;
    const int j = flat >> 3;
    const int m0 = ((flat & 7) * 8 + (j & 7)) * 128;
    const int n0 = (j >> 3) * 128;

    f32x4 acc[4][4];
    #pragma unroll
    for (int mi = 0; mi < 4; mi++)
        #pragma unroll
        for (int ni = 0; ni < 4; ni++)
            acc[mi][ni][0] = acc[mi][ni][1] = acc[mi][ni][2] = acc[mi][ni][3] = 0.f;

    for (int k0 = 0; k0 < K_; k0 += 32) {
        #pragma unroll
        for (int i = 0; i < 2; i++) {
            const int o_ = w * 2048 + i * 1024 + l * 16;
            const int row = o_ >> 6, colb = o_ & 63;
            const char* ga = (const char*)A  + (((size_t)(m0 + row)) * K_ + k0) * 2 + colb;
            const char* gb = (const char*)Bw + (((size_t)(n0 + row)) * K_ + k0) * 2 + colb;
            GLDS16(ga, (char*)As + w * 2048 + i * 1024);
            GLDS16(gb, (char*)Bs + w * 2048 + i * 1024);
        }
        __syncthreads();

        bf16x8 af[4], bfr[4];
        #pragma unroll
        for (int mi = 0; mi < 4; mi++)
            af[mi] = *(const bf16x8*)&As[(wm * 64 + mi * 16 + l16) * 32 + lg * 8];
        #pragma unroll
        for (int ni = 0; ni < 4; ni++)
            bfr[ni] = *(const bf16x8*)&Bs[(wn * 64 + ni * 16 + l16) * 32 + lg * 8];
        #pragma unroll
        for (int mi = 0; mi < 4; mi++)
            #pragma unroll
            for (int ni = 0; ni < 4; ni++)
                acc[mi][ni] = __builtin_amdgcn_mfma_f32_16x16x32_bf16(af[mi], bfr[ni], acc[mi][ni], 0, 0, 0);
        __syncthreads();
    }

    float bcol[4];
    #pragma unroll
    for (int ni = 0; ni < 4; ni++) bcol[ni] = bias[n0 + wn * 64 + ni * 16 + l16];
    #pragma unroll
    for (int mi = 0; mi < 4; mi++) {
        #pragma unroll
        for (int r = 0; r < 4; r++) {
            const int row = m0 + wm * 64 + mi * 16 + lg * 4 + r;
            #pragma unroll
            for (int ni = 0; ni < 4; ni++) {
                const int col = n0 + wn * 64 + ni * 16 + l16;
                o[(size_t)row * H_ + col] = acc[mi][ni][r] + bcol[ni] + res[(size_t)row * H_ + col];
            }
        }
    }
}

// ---------------------------------------------------------------------------
// MFMA flash attention: Q-block 128 = 8 waves x 16 q-rows, KV tile 64.
// R16 structure, but P goes through a VOLATILE, single-typed (u64) LDS
// buffer: volatile forbids compile-time elision/reordering of the
// cross-lane ds ops (the R8-R15 hazard); same-type access kills TBAA
// ambiguity; per-wave LDS ops execute in order in HW -> race-free with
// no barrier.  4x ds_write_b64 + 4x ds_read_b64 per tile (vs 16 bpermute).
// u64 idx 4n+lg holds (pkl[n],pkh[n]) = kc 16n+4lg+{0..3}; read idx
// 2lg,2lg+1 (+8 for pa1) = kc 8lg..8lg+7.  Same XOR swizzle both sides.
// ---------------------------------------------------------------------------
__global__ __launch_bounds__(512)
void flash_attn_mfma(const short* __restrict__ q, const short* __restrict__ k,
                     const short* __restrict__ vt, const float* __restrict__ mask,
                     short* __restrict__ ctx) {
    const int qt = blockIdx.x, h = blockIdx.y, b = blockIdx.z;
    __shared__ __align__(16) short KsL[2][4096];        // [buf][64 s][128B] swz
    __shared__ __align__(16) short VtL[2][4096];        // [buf][64 d][128B] swz
    __shared__ __align__(16) unsigned long long PsU[128 * 16];  // [128 rows][16 u64]
    const int tid = threadIdx.x;
    const int w = tid >> 6, l = tid & 63;
    const int l16 = l & 15, lg = l >> 4;

    const size_t bh = (size_t)(b * NH_ + h);
    bf16x8 qf0, qf1;
    {
        const size_t qr = (bh * S_ + (size_t)qt * 128 + w * 16 + l16) * HD_;
        qf0 = *(const bf16x8*)(q + qr + lg * 8);
        qf1 = *(const bf16x8*)(q + qr + 32 + lg * 8);
    }
    const size_t kbase  = bh * S_ * HD_;   // K  [s][d]
    const size_t vtbase = bh * HD_ * S_;   // Vt [d][s]

    bf16x8 ones;
    #pragma unroll
    for (int jj = 0; jj < 8; jj++) ones[jj] = (short)0x3F80;

    f32x4 oacc[4], lsum;
    #pragma unroll
    for (int i = 0; i < 4; i++) oacc[i][0] = oacc[i][1] = oacc[i][2] = oacc[i][3] = 0.f;
    lsum[0] = lsum[1] = lsum[2] = lsum[3] = 0.f;
    float m_reg = -3.0e38f;

    // staging: 512 threads x 16B = one full 8KB tile each for K and Vt
    const int srow = tid >> 3;             // 0..63
    const int sc0  = (tid & 7) * 16;       // byte col within 128B row
    const int wr0  = (srow << 7) + (sc0 ^ ((srow & 7) << 4));

    // P LDS geometry (u64 units)
    const int prow = w * 16 + l16;         // this lane's P row (0..127)
    const int pu_base = prow * 16;
    const int pu_swz  = (prow & 7) << 1;   // 16B granule swizzle in u64 units
    volatile unsigned long long* pP = PsU;

    bf16x8 nk, nv;
    #define LOADT(ct_) do {                                                        \
        nk = *(const bf16x8*)((const char*)(k  + kbase  + (size_t)((ct_) * 64 + srow) * HD_) + sc0); \
        nv = *(const bf16x8*)((const char*)(vt + vtbase + (size_t)srow * S_ + (ct_) * 64) + sc0);    \
    } while (0)
    #define WRITET(bu_) do {                                                       \
        *(bf16x8*)((char*)KsL[bu_] + wr0) = nk;                                    \
        *(bf16x8*)((char*)VtL[bu_] + wr0) = nv;                                    \
    } while (0)

    LOADT(0);
    WRITET(0);
    __syncthreads();

    int cbuf = 0;
    for (int ct = 0; ct < S_ / 64; ct++) {
        if (ct + 1 < S_ / 64) LOADT(ct + 1);   // issue early: hide under compute

        // ---- S^T = mfma(K, Q) with C initialized to the (log2-scaled) mask ----
        f32x4 sacc[4];
        #pragma unroll
        for (int n = 0; n < 4; n++) {
            float4 mk = *(const float4*)(mask + (size_t)b * S_ + ct * 64 + n * 16 + lg * 4);
            sacc[n][0] = mk.x; sacc[n][1] = mk.y; sacc[n][2] = mk.z; sacc[n][3] = mk.w;
        }
        __builtin_amdgcn_s_setprio(1);
        #pragma unroll
        for (int n = 0; n < 4; n++) {
            bf16x8 kb0 = *LDSRD(KsL[cbuf], n * 16 + l16, lg * 16);
            bf16x8 kb1 = *LDSRD(KsL[cbuf], n * 16 + l16, 64 + lg * 16);
            sacc[n] = __builtin_amdgcn_mfma_f32_16x16x32_bf16(kb0, qf0, sacc[n], 0, 0, 0);
            sacc[n] = __builtin_amdgcn_mfma_f32_16x16x32_bf16(kb1, qf1, sacc[n], 0, 0, 0);
        }
        __builtin_amdgcn_s_setprio(0);

        // ---- lane-local max for q-row l16 ----
        float x0 = fmaxf(fmaxf(sacc[0][0], sacc[0][1]), fmaxf(sacc[0][2], sacc[0][3]));
        float x1 = fmaxf(fmaxf(sacc[1][0], sacc[1][1]), fmaxf(sacc[1][2], sacc[1][3]));
        float x2 = fmaxf(fmaxf(sacc[2][0], sacc[2][1]), fmaxf(sacc[2][2], sacc[2][3]));
        float x3 = fmaxf(fmaxf(sacc[3][0], sacc[3][1]), fmaxf(sacc[3][2], sacc[3][3]));
        float pmax = fmaxf(fmaxf(x0, x1), fmaxf(x2, x3));
        pmax = fmaxf(pmax, __shfl_xor(pmax, 16));
        pmax = fmaxf(pmax, __shfl_xor(pmax, 32));

        // ---- defer-max rescale (T13) ----
        if (!__all(pmax - m_reg <= 8.f)) {
            const float mn = fmaxf(m_reg, pmax);
            const float corr = __builtin_amdgcn_exp2f(m_reg - mn);
            m_reg = mn;
            float corr4[4];
            #pragma unroll
            for (int r = 0; r < 4; r++) corr4[r] = __shfl(corr, lg * 4 + r);
            #pragma unroll
            for (int nd = 0; nd < 4; nd++)
                #pragma unroll
                for (int r = 0; r < 4; r++) oacc[nd][r] *= corr4[r];
            #pragma unroll
            for (int r = 0; r < 4; r++) lsum[r] *= corr4[r];
        }

        // ---- P = exp2(s - m): pack and store via volatile u64 LDS ----
        #pragma unroll
        for (int n = 0; n < 4; n++) {
            unsigned lo = cvt_pk_bf16(__builtin_amdgcn_exp2f(sacc[n][0] - m_reg),
                                      __builtin_amdgcn_exp2f(sacc[n][1] - m_reg));
            unsigned hi = cvt_pk_bf16(__builtin_amdgcn_exp2f(sacc[n][2] - m_reg),
                                      __builtin_amdgcn_exp2f(sacc[n][3] - m_reg));
            pP[pu_base + ((4 * n + lg) ^ pu_swz)] =
                ((unsigned long long)hi << 32) | (unsigned long long)lo;
        }

        // ---- rebuild PV A-fragments (volatile u64 reads, same type) ----
        unsigned long long t0 = pP[pu_base + ((2 * lg)     ^ pu_swz)];
        unsigned long long t1 = pP[pu_base + ((2 * lg + 1) ^ pu_swz)];
        unsigned long long t2 = pP[pu_base + ((8 + 2 * lg)     ^ pu_swz)];
        unsigned long long t3 = pP[pu_base + ((8 + 2 * lg + 1) ^ pu_swz)];
        union U8 { unsigned u[4]; bf16x8 v; } A0, A1;
        A0.u[0] = (unsigned)t0; A0.u[1] = (unsigned)(t0 >> 32);
        A0.u[2] = (unsigned)t1; A0.u[3] = (unsigned)(t1 >> 32);
        A1.u[0] = (unsigned)t2; A1.u[1] = (unsigned)(t2 >> 32);
        A1.u[2] = (unsigned)t3; A1.u[3] = (unsigned)(t3 >> 32);
        bf16x8 pa0 = A0.v, pa1 = A1.v;

        // ---- O += P V ; l += P 1 ----
        __builtin_amdgcn_s_setprio(1);
        lsum = __builtin_amdgcn_mfma_f32_16x16x32_bf16(pa0, ones, lsum, 0, 0, 0);
        lsum = __builtin_amdgcn_mfma_f32_16x16x32_bf16(pa1, ones, lsum, 0, 0, 0);
        #pragma unroll
        for (int nd = 0; nd < 4; nd++) {
            bf16x8 vb0 = *LDSRD(VtL[cbuf], nd * 16 + l16, lg * 16);
            bf16x8 vb1 = *LDSRD(VtL[cbuf], nd * 16 + l16, 64 + lg * 16);
            oacc[nd] = __builtin_amdgcn_mfma_f32_16x16x32_bf16(pa0, vb0, oacc[nd], 0, 0, 0);
            oacc[nd] = __builtin_amdgcn_mfma_f32_16x16x32_bf16(pa1, vb1, oacc[nd], 0, 0, 0);
        }
        __builtin_amdgcn_s_setprio(0);

        // ---- write-late: staged regs -> other buffer ----
        if (ct + 1 < S_ / 64) WRITET(cbuf ^ 1);
        __syncthreads();   // publish next buffer / protect K,V reads
        cbuf ^= 1;
    }
    #undef LOADT
    #undef WRITET

    // ---- normalize + write ctx bf16 [M][H] (lsum already in O-layout) ----
    #pragma unroll
    for (int r = 0; r < 4; r++) {
        const float inv = 1.f / lsum[r];
        const size_t row = (size_t)(b * S_ + qt * 128 + w * 16 + lg * 4 + r);
        #pragma unroll
        for (int nd = 0; nd < 4; nd++)
            ctx[row * H_ + h * HD_ + nd * 16 + l16] = f2bf(oacc[nd][r] * inv);
    }
}

// ---------------------------------------------------------------------------
// LayerNorm over last dim (768). One block (256 thr) per row.
// ---------------------------------------------------------------------------
__global__ __launch_bounds__(256)
void layernorm_k(const float* __restrict__ hin, const float* __restrict__ g,
                 const float* __restrict__ beta, float* __restrict__ out) {
    const int row = blockIdx.x;
    const int tid = threadIdx.x;
    const float* x = hin + (size_t)row * H_;
    __shared__ float sm[4];

    float v0 = x[tid], v1 = x[tid + 256], v2 = x[tid + 512];
    float s = v0 + v1 + v2;
    #pragma unroll
    for (int o = 32; o > 0; o >>= 1) s += __shfl_xor(s, o);
    if ((tid & 63) == 0) sm[tid >> 6] = s;
    __syncthreads();
    float mu = (sm[0] + sm[1] + sm[2] + sm[3]) * (1.f / 768.f);

    float d0 = v0 - mu, d1 = v1 - mu, d2 = v2 - mu;
    float ss = d0*d0 + d1*d1 + d2*d2;
    #pragma unroll
    for (int o = 32; o > 0; o >>= 1) ss += __shfl_xor(ss, o);
    __syncthreads();
    if ((tid & 63) == 0) sm[tid >> 6] = ss;
    __syncthreads();
    float var = (sm[0] + sm[1] + sm[2] + sm[3]) * (1.f / 768.f);
    float sc = rsqrtf(var + 1e-12f);

    float* y = out + (size_t)row * H_;
    y[tid]       = d0 * sc * g[tid]       + beta[tid];
    y[tid + 256] = d1 * sc * g[tid + 256] + beta[tid + 256];
    y[tid + 512] = d2 * sc * g[tid + 512] + beta[tid + 512];
}

// ---------------------------------------------------------------------------
extern "C" void kernel_launch(void* const* d_in, const int* in_sizes, int n_in,
                              void* d_out, int out_size, void* d_ws, size_t ws_size,
                              hipStream_t stream) {
    const float* hs   = (const float*)d_in[0];
    const float* mask = (const float*)d_in[1];
    const float* Wq   = (const float*)d_in[2];
    const float* bq   = (const float*)d_in[3];
    const float* Wk   = (const float*)d_in[4];
    const float* bk   = (const float*)d_in[5];
    const float* Wv   = (const float*)d_in[6];
    const float* bv   = (const float*)d_in[7];
    const float* Wo   = (const float*)d_in[8];
    const float* bo   = (const float*)d_in[9];
    const float* ln_g = (const float*)d_in[10];
    const float* ln_b = (const float*)d_in[11];
    float* out = (float*)d_out;

    const size_t MH = (size_t)M_ * H_;
    const size_t HH = (size_t)H_ * H_;
    short* hsbf = (short*)d_ws;       // [M][768] bf16
    short* wqbf = hsbf + MH;          // [2304][768] consecutive Wq,Wk,Wv
    short* wkbf = wqbf + HH;
    short* wvbf = wkbf + HH;
    short* wobf = wvbf + HH;
    short* qbf  = wobf + HH;          // [b][h][s][d] bf16; q,k consecutive
    short* kbf  = qbf + MH;
    short* vtb  = kbf + MH;           // [b][h][d][s] (written by gemm_qkv)
    short* cbf  = vtb + MH;           // ctx bf16 [M][768]
    float* hb   = (float*)(cbf + MH); // fp32 [M][768]
    float* msk2 = hb + MH;            // mask * log2e (8192 fp32)

    cvt6<<<dim3(256, 6), 256, 0, stream>>>(hs, Wq, Wk, Wv, Wo, mask,
                                           hsbf, wqbf, wkbf, wvbf, wobf, msk2);

    gemm_qkv<<<dim3(1152), 256, 0, stream>>>(hsbf, wqbf, bq, bk, bv, qbf, vtb);

    flash_attn_mfma<<<dim3(S_ / 128, NH_, B_), 512, 0, stream>>>(qbf, kbf, vtb, msk2, cbf);

    gemm_out<<<dim3(384), 256, 0, stream>>>(cbf, wobf, bo, hs, hb);

    layernorm_k<<<M_, 256, 0, stream>>>(hb, ln_g, ln_b, out);
}

// Round 20
// 188.196 us; speedup vs baseline: 1.1375x; 1.1375x over previous
//
#include <hip/hip_runtime.h>
#include <math.h>

#define B_  4
#define S_  2048
#define H_  768
#define NH_ 12
#define HD_ 64
#define M_  (B_*S_)   // 8192
#define K_  768
#define LOG2E 1.44269504088896340736f

using bf16x8 = __attribute__((ext_vector_type(8))) short;
using s16x4  = __attribute__((ext_vector_type(4))) short;
using f32x4  = __attribute__((ext_vector_type(4))) float;

__device__ inline short f2bf(float f) {
    union { float f; unsigned u; } v{f};
    unsigned r = (v.u + 0x7FFF + ((v.u >> 16) & 1)) >> 16;   // RNE
    return (short)r;
}

__device__ inline unsigned cvt_pk_bf16(float lo, float hi) {
    unsigned r;
    asm("v_cvt_pk_bf16_f32 %0, %1, %2" : "=v"(r) : "v"(lo), "v"(hi));
    return r;
}

#define GLDS16(g, l) __builtin_amdgcn_global_load_lds( \
    (const __attribute__((address_space(1))) void*)(g), \
    (__attribute__((address_space(3))) void*)(l), 16, 0, 0)

// swizzled LDS read: linear [R][128B] tile, byte ^= ((row&7)<<4)
__device__ inline const bf16x8* LDSRD(const short* base, int row, int colByte) {
    return (const bf16x8*)((const char*)base + ((row << 7) + (colByte ^ ((row & 7) << 4))));
}

// ---------------------------------------------------------------------------
// fp32 -> bf16 conversion (regions 0-4: hs, Wq, Wk, Wv, Wo) + mask*log2e (5)
// ---------------------------------------------------------------------------
__global__ __launch_bounds__(256)
void cvt6(const float* __restrict__ s0, const float* __restrict__ s1,
          const float* __restrict__ s2, const float* __restrict__ s3,
          const float* __restrict__ s4, const float* __restrict__ msk,
          short* __restrict__ d0, short* __restrict__ d1,
          short* __restrict__ d2, short* __restrict__ d3,
          short* __restrict__ d4, float* __restrict__ msk2) {
    const int r = blockIdx.y;
    if (r == 5) {
        for (int i = blockIdx.x * blockDim.x + threadIdx.x; i < (B_ * S_) / 4;
             i += gridDim.x * blockDim.x) {
            float4 v = ((const float4*)msk)[i];
            v.x *= LOG2E; v.y *= LOG2E; v.z *= LOG2E; v.w *= LOG2E;
            ((float4*)msk2)[i] = v;
        }
        return;
    }
    const float* s = r == 0 ? s0 : r == 1 ? s1 : r == 2 ? s2 : r == 3 ? s3 : s4;
    short* d      = r == 0 ? d0 : r == 1 ? d1 : r == 2 ? d2 : r == 3 ? d3 : d4;
    const int n4  = (r == 0 ? M_ * H_ : H_ * H_) >> 2;
    for (int i = blockIdx.x * blockDim.x + threadIdx.x; i < n4; i += gridDim.x * blockDim.x) {
        float4 v = ((const float4*)s)[i];
        s16x4 o;
        o[0] = f2bf(v.x); o[1] = f2bf(v.y); o[2] = f2bf(v.z); o[3] = f2bf(v.w);
        ((s16x4*)d)[i] = o;
    }
}

// ---------------------------------------------------------------------------
// Fused QKV GEMM, XCD-chunked 1-D grid (1152 blocks).
// Q/K -> bf16 head-major [b][h][s][d]; V -> transposed [b][h][d][s].
// ---------------------------------------------------------------------------
__global__ __launch_bounds__(256)
void gemm_qkv(const short* __restrict__ A, const short* __restrict__ Bw,
              const float* __restrict__ bq, const float* __restrict__ bk,
              const float* __restrict__ bv, short* __restrict__ obase,
              short* __restrict__ vt) {
    __shared__ __align__(16) short As[128 * 32];
    __shared__ __align__(16) short Bs[128 * 32];
    const int tid = threadIdx.x;
    const int w = tid >> 6, l = tid & 63;
    const int l16 = l & 15, lg = l >> 4;
    const int wm = w >> 1, wn = w & 1;
    const int flat = blockIdx.x;
    const int j = flat >> 3;
    const int mt = (flat & 7) * 8 + (j & 7);
    const int nty = j >> 3;                    // 0..17
    const int m0 = mt * 128, n0 = nty * 128;
    const int which = nty / 6;
    const float* bias = which == 0 ? bq : which == 1 ? bk : bv;
    const float scale = which == 0 ? 0.125f * LOG2E : 1.0f;

    f32x4 acc[4][4];
    #pragma unroll
    for (int mi = 0; mi < 4; mi++)
        #pragma unroll
        for (int ni = 0; ni < 4; ni++)
            acc[mi][ni][0] = acc[mi][ni][1] = acc[mi][ni][2] = acc[mi][ni][3] = 0.f;

    for (int k0 = 0; k0 < K_; k0 += 32) {
        #pragma unroll
        for (int i = 0; i < 2; i++) {
            const int o = w * 2048 + i * 1024 + l * 16;
            const int row = o >> 6, colb = o & 63;
            const char* ga = (const char*)A  + (((size_t)(m0 + row)) * K_ + k0) * 2 + colb;
            const char* gb = (const char*)Bw + (((size_t)(n0 + row)) * K_ + k0) * 2 + colb;
            GLDS16(ga, (char*)As + w * 2048 + i * 1024);
            GLDS16(gb, (char*)Bs + w * 2048 + i * 1024);
        }
        __syncthreads();

        bf16x8 af[4], bfr[4];
        #pragma unroll
        for (int mi = 0; mi < 4; mi++)
            af[mi] = *(const bf16x8*)&As[(wm * 64 + mi * 16 + l16) * 32 + lg * 8];
        #pragma unroll
        for (int ni = 0; ni < 4; ni++)
            bfr[ni] = *(const bf16x8*)&Bs[(wn * 64 + ni * 16 + l16) * 32 + lg * 8];
        #pragma unroll
        for (int mi = 0; mi < 4; mi++)
            #pragma unroll
            for (int ni = 0; ni < 4; ni++)
                acc[mi][ni] = __builtin_amdgcn_mfma_f32_16x16x32_bf16(af[mi], bfr[ni], acc[mi][ni], 0, 0, 0);
        __syncthreads();
    }

    const int ncol0 = (nty % 6) * 128;
    float bcol[4];
    #pragma unroll
    for (int ni = 0; ni < 4; ni++) bcol[ni] = bias[ncol0 + wn * 64 + ni * 16 + l16];

    const int h = (nty % 6) * 2 + wn;   // wave's 64-col span == one head
    if (which < 2) {
        short* obf = obase + (size_t)which * M_ * H_;
        #pragma unroll
        for (int mi = 0; mi < 4; mi++) {
            #pragma unroll
            for (int r = 0; r < 4; r++) {
                const int row = m0 + wm * 64 + mi * 16 + lg * 4 + r;
                const int bb = row >> 11, ss = row & 2047;
                const size_t base = (((size_t)(bb * NH_ + h)) * S_ + ss) * HD_;
                #pragma unroll
                for (int ni = 0; ni < 4; ni++)
                    obf[base + ni * 16 + l16] = f2bf((acc[mi][ni][r] + bcol[ni]) * scale);
            }
        }
    } else {
        // V: transposed store [b][h][d][s]
        #pragma unroll
        for (int mi = 0; mi < 4; mi++) {
            const int row0 = m0 + wm * 64 + mi * 16 + lg * 4;
            const int bb = row0 >> 11, ss0 = row0 & 2047;
            #pragma unroll
            for (int ni = 0; ni < 4; ni++) {
                s16x4 pk;
                pk[0] = f2bf(acc[mi][ni][0] + bcol[ni]);
                pk[1] = f2bf(acc[mi][ni][1] + bcol[ni]);
                pk[2] = f2bf(acc[mi][ni][2] + bcol[ni]);
                pk[3] = f2bf(acc[mi][ni][3] + bcol[ni]);
                *(s16x4*)(vt + (((size_t)(bb * NH_ + h)) * HD_ + ni * 16 + l16) * S_ + ss0) = pk;
            }
        }
    }
}

// ---------------------------------------------------------------------------
// O-proj GEMM, XCD-chunked 1-D grid (384 blocks).
// ---------------------------------------------------------------------------
__global__ __launch_bounds__(256)
void gemm_out(const short* __restrict__ A, const short* __restrict__ Bw,
              const float* __restrict__ bias, const float* __restrict__ res,
              float* __restrict__ o) {
    __shared__ __align__(16) short As[128 * 32];
    __shared__ __align__(16) short Bs[128 * 32];
    const int tid = threadIdx.x;
    const int w = tid >> 6, l = tid & 63;
    const int l16 = l & 15, lg = l >> 4;
    const int wm = w >> 1, wn = w & 1;
    const int flat = blockIdx.x;
    const int j = flat >> 3;
    const int m0 = ((flat & 7) * 8 + (j & 7)) * 128;
    const int n0 = (j >> 3) * 128;

    f32x4 acc[4][4];
    #pragma unroll
    for (int mi = 0; mi < 4; mi++)
        #pragma unroll
        for (int ni = 0; ni < 4; ni++)
            acc[mi][ni][0] = acc[mi][ni][1] = acc[mi][ni][2] = acc[mi][ni][3] = 0.f;

    for (int k0 = 0; k0 < K_; k0 += 32) {
        #pragma unroll
        for (int i = 0; i < 2; i++) {
            const int o_ = w * 2048 + i * 1024 + l * 16;
            const int row = o_ >> 6, colb = o_ & 63;
            const char* ga = (const char*)A  + (((size_t)(m0 + row)) * K_ + k0) * 2 + colb;
            const char* gb = (const char*)Bw + (((size_t)(n0 + row)) * K_ + k0) * 2 + colb;
            GLDS16(ga, (char*)As + w * 2048 + i * 1024);
            GLDS16(gb, (char*)Bs + w * 2048 + i * 1024);
        }
        __syncthreads();

        bf16x8 af[4], bfr[4];
        #pragma unroll
        for (int mi = 0; mi < 4; mi++)
            af[mi] = *(const bf16x8*)&As[(wm * 64 + mi * 16 + l16) * 32 + lg * 8];
        #pragma unroll
        for (int ni = 0; ni < 4; ni++)
            bfr[ni] = *(const bf16x8*)&Bs[(wn * 64 + ni * 16 + l16) * 32 + lg * 8];
        #pragma unroll
        for (int mi = 0; mi < 4; mi++)
            #pragma unroll
            for (int ni = 0; ni < 4; ni++)
                acc[mi][ni] = __builtin_amdgcn_mfma_f32_16x16x32_bf16(af[mi], bfr[ni], acc[mi][ni], 0, 0, 0);
        __syncthreads();
    }

    float bcol[4];
    #pragma unroll
    for (int ni = 0; ni < 4; ni++) bcol[ni] = bias[n0 + wn * 64 + ni * 16 + l16];
    #pragma unroll
    for (int mi = 0; mi < 4; mi++) {
        #pragma unroll
        for (int r = 0; r < 4; r++) {
            const int row = m0 + wm * 64 + mi * 16 + lg * 4 + r;
            #pragma unroll
            for (int ni = 0; ni < 4; ni++) {
                const int col = n0 + wn * 64 + ni * 16 + l16;
                o[(size_t)row * H_ + col] = acc[mi][ni][r] + bcol[ni] + res[(size_t)row * H_ + col];
            }
        }
    }
}

// ---------------------------------------------------------------------------
// MFMA flash attention: Q-block 128 = 8 waves x 16 q-rows, KV tile 64.
// P round-trip through same-typed (uint2) LDS with BOTH compile-time
// fences (asm memory clobber + sched_barrier) AND a hardware fence:
// s_waitcnt lgkmcnt(0) between the P ds_writes and ds_reads.  R19 proved
// the residual corruption is a RUNTIME race (same binary, different
// results across replays): LDS same-wave write->read of the same bytes is
// not ordered unless the write has drained (reads can bypass in-flight
// writes in the LDS queues).  R17's volatile was stable-correct because
// the backend drains around every volatile access; this does it once per
// tile instead.
// ---------------------------------------------------------------------------
__global__ __launch_bounds__(512)
void flash_attn_mfma(const short* __restrict__ q, const short* __restrict__ k,
                     const short* __restrict__ vt, const float* __restrict__ mask,
                     short* __restrict__ ctx) {
    const int qt = blockIdx.x, h = blockIdx.y, b = blockIdx.z;
    __shared__ __align__(16) short KsL[2][4096];   // [buf][64 s][128B] swz
    __shared__ __align__(16) short VtL[2][4096];   // [buf][64 d][128B] swz
    __shared__ __align__(16) uint2 PsP[128 * 16];  // [128 rows][16 uint2]
    const int tid = threadIdx.x;
    const int w = tid >> 6, l = tid & 63;
    const int l16 = l & 15, lg = l >> 4;

    const size_t bh = (size_t)(b * NH_ + h);
    bf16x8 qf0, qf1;
    {
        const size_t qr = (bh * S_ + (size_t)qt * 128 + w * 16 + l16) * HD_;
        qf0 = *(const bf16x8*)(q + qr + lg * 8);
        qf1 = *(const bf16x8*)(q + qr + 32 + lg * 8);
    }
    const size_t kbase  = bh * S_ * HD_;   // K  [s][d]
    const size_t vtbase = bh * HD_ * S_;   // Vt [d][s]

    bf16x8 ones;
    #pragma unroll
    for (int jj = 0; jj < 8; jj++) ones[jj] = (short)0x3F80;

    f32x4 oacc[4], lsum;
    #pragma unroll
    for (int i = 0; i < 4; i++) oacc[i][0] = oacc[i][1] = oacc[i][2] = oacc[i][3] = 0.f;
    lsum[0] = lsum[1] = lsum[2] = lsum[3] = 0.f;
    float m_reg = -3.0e38f;

    // staging: 512 threads x 16B = one full 8KB tile each for K and Vt
    const int srow = tid >> 3;             // 0..63
    const int sc0  = (tid & 7) * 16;       // byte col within 128B row
    const int wr0  = (srow << 7) + (sc0 ^ ((srow & 7) << 4));

    // P LDS geometry (uint2 units)
    const int prow = w * 16 + l16;         // this lane's P row (0..127)
    const int pu_base = prow * 16;

    bf16x8 nk, nv;
    #define LOADT(ct_) do {                                                        \
        nk = *(const bf16x8*)((const char*)(k  + kbase  + (size_t)((ct_) * 64 + srow) * HD_) + sc0); \
        nv = *(const bf16x8*)((const char*)(vt + vtbase + (size_t)srow * S_ + (ct_) * 64) + sc0);    \
    } while (0)
    #define WRITET(bu_) do {                                                       \
        *(bf16x8*)((char*)KsL[bu_] + wr0) = nk;                                    \
        *(bf16x8*)((char*)VtL[bu_] + wr0) = nv;                                    \
    } while (0)

    LOADT(0);
    WRITET(0);
    __syncthreads();

    int cbuf = 0;
    for (int ct = 0; ct < S_ / 64; ct++) {
        if (ct + 1 < S_ / 64) LOADT(ct + 1);   // issue early: hide under compute

        // ---- S^T = mfma(K, Q) with C initialized to the (log2-scaled) mask ----
        f32x4 sacc[4];
        #pragma unroll
        for (int n = 0; n < 4; n++) {
            float4 mk = *(const float4*)(mask + (size_t)b * S_ + ct * 64 + n * 16 + lg * 4);
            sacc[n][0] = mk.x; sacc[n][1] = mk.y; sacc[n][2] = mk.z; sacc[n][3] = mk.w;
        }
        __builtin_amdgcn_s_setprio(1);
        #pragma unroll
        for (int n = 0; n < 4; n++) {
            bf16x8 kb0 = *LDSRD(KsL[cbuf], n * 16 + l16, lg * 16);
            bf16x8 kb1 = *LDSRD(KsL[cbuf], n * 16 + l16, 64 + lg * 16);
            sacc[n] = __builtin_amdgcn_mfma_f32_16x16x32_bf16(kb0, qf0, sacc[n], 0, 0, 0);
            sacc[n] = __builtin_amdgcn_mfma_f32_16x16x32_bf16(kb1, qf1, sacc[n], 0, 0, 0);
        }
        __builtin_amdgcn_s_setprio(0);

        // ---- lane-local max for q-row l16 ----
        float x0 = fmaxf(fmaxf(sacc[0][0], sacc[0][1]), fmaxf(sacc[0][2], sacc[0][3]));
        float x1 = fmaxf(fmaxf(sacc[1][0], sacc[1][1]), fmaxf(sacc[1][2], sacc[1][3]));
        float x2 = fmaxf(fmaxf(sacc[2][0], sacc[2][1]), fmaxf(sacc[2][2], sacc[2][3]));
        float x3 = fmaxf(fmaxf(sacc[3][0], sacc[3][1]), fmaxf(sacc[3][2], sacc[3][3]));
        float pmax = fmaxf(fmaxf(x0, x1), fmaxf(x2, x3));
        pmax = fmaxf(pmax, __shfl_xor(pmax, 16));
        pmax = fmaxf(pmax, __shfl_xor(pmax, 32));

        // ---- defer-max rescale (T13) ----
        if (!__all(pmax - m_reg <= 8.f)) {
            const float mn = fmaxf(m_reg, pmax);
            const float corr = __builtin_amdgcn_exp2f(m_reg - mn);
            m_reg = mn;
            float corr4[4];
            #pragma unroll
            for (int r = 0; r < 4; r++) corr4[r] = __shfl(corr, lg * 4 + r);
            #pragma unroll
            for (int nd = 0; nd < 4; nd++)
                #pragma unroll
                for (int r = 0; r < 4; r++) oacc[nd][r] *= corr4[r];
            #pragma unroll
            for (int r = 0; r < 4; r++) lsum[r] *= corr4[r];
        }

        // ---- P = exp2(s - m): pack and store (same-typed uint2 LDS) ----
        #pragma unroll
        for (int n = 0; n < 4; n++) {
            uint2 pk;
            pk.x = cvt_pk_bf16(__builtin_amdgcn_exp2f(sacc[n][0] - m_reg),
                               __builtin_amdgcn_exp2f(sacc[n][1] - m_reg));
            pk.y = cvt_pk_bf16(__builtin_amdgcn_exp2f(sacc[n][2] - m_reg),
                               __builtin_amdgcn_exp2f(sacc[n][3] - m_reg));
            PsP[pu_base + ((4 * n + lg) ^ l16)] = pk;
        }
        // Compile-time fence (no elision/hoist across) ...
        asm volatile("" ::: "memory");
        // ... plus HARDWARE fence: drain the P ds_writes before any P ds_read
        // issues (LDS write->read of same bytes is not otherwise ordered).
        asm volatile("s_waitcnt lgkmcnt(0)" ::: "memory");
        __builtin_amdgcn_sched_barrier(0);

        // ---- rebuild PV A-fragments (same-typed uint2 reads) ----
        uint2 r0 = PsP[pu_base + ((2 * lg)     ^ l16)];
        uint2 r1 = PsP[pu_base + ((2 * lg + 1) ^ l16)];
        uint2 r2 = PsP[pu_base + ((8 + 2 * lg)     ^ l16)];
        uint2 r3 = PsP[pu_base + ((8 + 2 * lg + 1) ^ l16)];
        asm volatile("" ::: "memory");
        __builtin_amdgcn_sched_barrier(0);
        union U8 { unsigned u[4]; bf16x8 v; } A0, A1;
        A0.u[0] = r0.x; A0.u[1] = r0.y; A0.u[2] = r1.x; A0.u[3] = r1.y;
        A1.u[0] = r2.x; A1.u[1] = r2.y; A1.u[2] = r3.x; A1.u[3] = r3.y;
        bf16x8 pa0 = A0.v, pa1 = A1.v;

        // ---- O += P V ; l += P 1 ----
        __builtin_amdgcn_s_setprio(1);
        lsum = __builtin_amdgcn_mfma_f32_16x16x32_bf16(pa0, ones, lsum, 0, 0, 0);
        lsum = __builtin_amdgcn_mfma_f32_16x16x32_bf16(pa1, ones, lsum, 0, 0, 0);
        #pragma unroll
        for (int nd = 0; nd < 4; nd++) {
            bf16x8 vb0 = *LDSRD(VtL[cbuf], nd * 16 + l16, lg * 16);
            bf16x8 vb1 = *LDSRD(VtL[cbuf], nd * 16 + l16, 64 + lg * 16);
            oacc[nd] = __builtin_amdgcn_mfma_f32_16x16x32_bf16(pa0, vb0, oacc[nd], 0, 0, 0);
            oacc[nd] = __builtin_amdgcn_mfma_f32_16x16x32_bf16(pa1, vb1, oacc[nd], 0, 0, 0);
        }
        __builtin_amdgcn_s_setprio(0);

        // ---- write-late: staged regs -> other buffer ----
        if (ct + 1 < S_ / 64) WRITET(cbuf ^ 1);
        __syncthreads();   // publish next buffer / protect K,V reads
        cbuf ^= 1;
    }
    #undef LOADT
    #undef WRITET

    // ---- normalize + write ctx bf16 [M][H] (lsum already in O-layout) ----
    #pragma unroll
    for (int r = 0; r < 4; r++) {
        const float inv = 1.f / lsum[r];
        const size_t row = (size_t)(b * S_ + qt * 128 + w * 16 + lg * 4 + r);
        #pragma unroll
        for (int nd = 0; nd < 4; nd++)
            ctx[row * H_ + h * HD_ + nd * 16 + l16] = f2bf(oacc[nd][r] * inv);
    }
}

// ---------------------------------------------------------------------------
// LayerNorm over last dim (768). One block (256 thr) per row.
// ---------------------------------------------------------------------------
__global__ __launch_bounds__(256)
void layernorm_k(const float* __restrict__ hin, const float* __restrict__ g,
                 const float* __restrict__ beta, float* __restrict__ out) {
    const int row = blockIdx.x;
    const int tid = threadIdx.x;
    const float* x = hin + (size_t)row * H_;
    __shared__ float sm[4];

    float v0 = x[tid], v1 = x[tid + 256], v2 = x[tid + 512];
    float s = v0 + v1 + v2;
    #pragma unroll
    for (int o = 32; o > 0; o >>= 1) s += __shfl_xor(s, o);
    if ((tid & 63) == 0) sm[tid >> 6] = s;
    __syncthreads();
    float mu = (sm[0] + sm[1] + sm[2] + sm[3]) * (1.f / 768.f);

    float d0 = v0 - mu, d1 = v1 - mu, d2 = v2 - mu;
    float ss = d0*d0 + d1*d1 + d2*d2;
    #pragma unroll
    for (int o = 32; o > 0; o >>= 1) ss += __shfl_xor(ss, o);
    __syncthreads();
    if ((tid & 63) == 0) sm[tid >> 6] = ss;
    __syncthreads();
    float var = (sm[0] + sm[1] + sm[2] + sm[3]) * (1.f / 768.f);
    float sc = rsqrtf(var + 1e-12f);

    float* y = out + (size_t)row * H_;
    y[tid]       = d0 * sc * g[tid]       + beta[tid];
    y[tid + 256] = d1 * sc * g[tid + 256] + beta[tid + 256];
    y[tid + 512] = d2 * sc * g[tid + 512] + beta[tid + 512];
}

// ---------------------------------------------------------------------------
extern "C" void kernel_launch(void* const* d_in, const int* in_sizes, int n_in,
                              void* d_out, int out_size, void* d_ws, size_t ws_size,
                              hipStream_t stream) {
    const float* hs   = (const float*)d_in[0];
    const float* mask = (const float*)d_in[1];
    const float* Wq   = (const float*)d_in[2];
    const float* bq   = (const float*)d_in[3];
    const float* Wk   = (const float*)d_in[4];
    const float* bk   = (const float*)d_in[5];
    const float* Wv   = (const float*)d_in[6];
    const float* bv   = (const float*)d_in[7];
    const float* Wo   = (const float*)d_in[8];
    const float* bo   = (const float*)d_in[9];
    const float* ln_g = (const float*)d_in[10];
    const float* ln_b = (const float*)d_in[11];
    float* out = (float*)d_out;

    const size_t MH = (size_t)M_ * H_;
    const size_t HH = (size_t)H_ * H_;
    short* hsbf = (short*)d_ws;       // [M][768] bf16
    short* wqbf = hsbf + MH;          // [2304][768] consecutive Wq,Wk,Wv
    short* wkbf = wqbf + HH;
    short* wvbf = wkbf + HH;
    short* wobf = wvbf + HH;
    short* qbf  = wobf + HH;          // [b][h][s][d] bf16; q,k consecutive
    short* kbf  = qbf + MH;
    short* vtb  = kbf + MH;           // [b][h][d][s] (written by gemm_qkv)
    short* cbf  = vtb + MH;           // ctx bf16 [M][768]
    float* hb   = (float*)(cbf + MH); // fp32 [M][768]
    float* msk2 = hb + MH;            // mask * log2e (8192 fp32)

    cvt6<<<dim3(256, 6), 256, 0, stream>>>(hs, Wq, Wk, Wv, Wo, mask,
                                           hsbf, wqbf, wkbf, wvbf, wobf, msk2);

    gemm_qkv<<<dim3(1152), 256, 0, stream>>>(hsbf, wqbf, bq, bk, bv, qbf, vtb);

    flash_attn_mfma<<<dim3(S_ / 128, NH_, B_), 512, 0, stream>>>(qbf, kbf, vtb, msk2, cbf);

    gemm_out<<<dim3(384), 256, 0, stream>>>(cbf, wobf, bo, hs, hb);

    layernorm_k<<<M_, 256, 0, stream>>>(hb, ln_g, ln_b, out);
}

// Round 21
// 185.370 us; speedup vs baseline: 1.1549x; 1.0152x over previous
//
#include <hip/hip_runtime.h>
#include <math.h>

#define B_  4
#define S_  2048
#define H_  768
#define NH_ 12
#define HD_ 64
#define M_  (B_*S_)   // 8192
#define K_  768
#define LOG2E 1.44269504088896340736f

using bf16x8 = __attribute__((ext_vector_type(8))) short;
using s16x4  = __attribute__((ext_vector_type(4))) short;
using f32x4  = __attribute__((ext_vector_type(4))) float;

__device__ inline short f2bf(float f) {
    union { float f; unsigned u; } v{f};
    unsigned r = (v.u + 0x7FFF + ((v.u >> 16) & 1)) >> 16;   // RNE
    return (short)r;
}

__device__ inline unsigned cvt_pk_bf16(float lo, float hi) {
    unsigned r;
    asm("v_cvt_pk_bf16_f32 %0, %1, %2" : "=v"(r) : "v"(lo), "v"(hi));
    return r;
}

#define GLDS16(g, l) __builtin_amdgcn_global_load_lds( \
    (const __attribute__((address_space(1))) void*)(g), \
    (__attribute__((address_space(3))) void*)(l), 16, 0, 0)

// swizzled LDS read: linear [R][128B] tile, byte ^= ((row&7)<<4)
__device__ inline const bf16x8* LDSRD(const short* base, int row, int colByte) {
    return (const bf16x8*)((const char*)base + ((row << 7) + (colByte ^ ((row & 7) << 4))));
}

// ---------------------------------------------------------------------------
// fp32 -> bf16 conversion (regions 0-4: hs, Wq, Wk, Wv, Wo) + mask*log2e (5)
// ---------------------------------------------------------------------------
__global__ __launch_bounds__(256)
void cvt6(const float* __restrict__ s0, const float* __restrict__ s1,
          const float* __restrict__ s2, const float* __restrict__ s3,
          const float* __restrict__ s4, const float* __restrict__ msk,
          short* __restrict__ d0, short* __restrict__ d1,
          short* __restrict__ d2, short* __restrict__ d3,
          short* __restrict__ d4, float* __restrict__ msk2) {
    const int r = blockIdx.y;
    if (r == 5) {
        for (int i = blockIdx.x * blockDim.x + threadIdx.x; i < (B_ * S_) / 4;
             i += gridDim.x * blockDim.x) {
            float4 v = ((const float4*)msk)[i];
            v.x *= LOG2E; v.y *= LOG2E; v.z *= LOG2E; v.w *= LOG2E;
            ((float4*)msk2)[i] = v;
        }
        return;
    }
    const float* s = r == 0 ? s0 : r == 1 ? s1 : r == 2 ? s2 : r == 3 ? s3 : s4;
    short* d      = r == 0 ? d0 : r == 1 ? d1 : r == 2 ? d2 : r == 3 ? d3 : d4;
    const int n4  = (r == 0 ? M_ * H_ : H_ * H_) >> 2;
    for (int i = blockIdx.x * blockDim.x + threadIdx.x; i < n4; i += gridDim.x * blockDim.x) {
        float4 v = ((const float4*)s)[i];
        s16x4 o;
        o[0] = f2bf(v.x); o[1] = f2bf(v.y); o[2] = f2bf(v.z); o[3] = f2bf(v.w);
        ((s16x4*)d)[i] = o;
    }
}

// ---------------------------------------------------------------------------
// Fused QKV GEMM, XCD-chunked 1-D grid (1152 blocks).
// Q/K -> bf16 head-major [b][h][s][d]; V -> transposed [b][h][d][s].
// ---------------------------------------------------------------------------
__global__ __launch_bounds__(256)
void gemm_qkv(const short* __restrict__ A, const short* __restrict__ Bw,
              const float* __restrict__ bq, const float* __restrict__ bk,
              const float* __restrict__ bv, short* __restrict__ obase,
              short* __restrict__ vt) {
    __shared__ __align__(16) short As[128 * 32];
    __shared__ __align__(16) short Bs[128 * 32];
    const int tid = threadIdx.x;
    const int w = tid >> 6, l = tid & 63;
    const int l16 = l & 15, lg = l >> 4;
    const int wm = w >> 1, wn = w & 1;
    const int flat = blockIdx.x;
    const int j = flat >> 3;
    const int mt = (flat & 7) * 8 + (j & 7);
    const int nty = j >> 3;                    // 0..17
    const int m0 = mt * 128, n0 = nty * 128;
    const int which = nty / 6;
    const float* bias = which == 0 ? bq : which == 1 ? bk : bv;
    const float scale = which == 0 ? 0.125f * LOG2E : 1.0f;

    f32x4 acc[4][4];
    #pragma unroll
    for (int mi = 0; mi < 4; mi++)
        #pragma unroll
        for (int ni = 0; ni < 4; ni++)
            acc[mi][ni][0] = acc[mi][ni][1] = acc[mi][ni][2] = acc[mi][ni][3] = 0.f;

    for (int k0 = 0; k0 < K_; k0 += 32) {
        #pragma unroll
        for (int i = 0; i < 2; i++) {
            const int o = w * 2048 + i * 1024 + l * 16;
            const int row = o >> 6, colb = o & 63;
            const char* ga = (const char*)A  + (((size_t)(m0 + row)) * K_ + k0) * 2 + colb;
            const char* gb = (const char*)Bw + (((size_t)(n0 + row)) * K_ + k0) * 2 + colb;
            GLDS16(ga, (char*)As + w * 2048 + i * 1024);
            GLDS16(gb, (char*)Bs + w * 2048 + i * 1024);
        }
        __syncthreads();

        bf16x8 af[4], bfr[4];
        #pragma unroll
        for (int mi = 0; mi < 4; mi++)
            af[mi] = *(const bf16x8*)&As[(wm * 64 + mi * 16 + l16) * 32 + lg * 8];
        #pragma unroll
        for (int ni = 0; ni < 4; ni++)
            bfr[ni] = *(const bf16x8*)&Bs[(wn * 64 + ni * 16 + l16) * 32 + lg * 8];
        #pragma unroll
        for (int mi = 0; mi < 4; mi++)
            #pragma unroll
            for (int ni = 0; ni < 4; ni++)
                acc[mi][ni] = __builtin_amdgcn_mfma_f32_16x16x32_bf16(af[mi], bfr[ni], acc[mi][ni], 0, 0, 0);
        __syncthreads();
    }

    const int ncol0 = (nty % 6) * 128;
    float bcol[4];
    #pragma unroll
    for (int ni = 0; ni < 4; ni++) bcol[ni] = bias[ncol0 + wn * 64 + ni * 16 + l16];

    const int h = (nty % 6) * 2 + wn;   // wave's 64-col span == one head
    if (which < 2) {
        short* obf = obase + (size_t)which * M_ * H_;
        #pragma unroll
        for (int mi = 0; mi < 4; mi++) {
            #pragma unroll
            for (int r = 0; r < 4; r++) {
                const int row = m0 + wm * 64 + mi * 16 + lg * 4 + r;
                const int bb = row >> 11, ss = row & 2047;
                const size_t base = (((size_t)(bb * NH_ + h)) * S_ + ss) * HD_;
                #pragma unroll
                for (int ni = 0; ni < 4; ni++)
                    obf[base + ni * 16 + l16] = f2bf((acc[mi][ni][r] + bcol[ni]) * scale);
            }
        }
    } else {
        // V: transposed store [b][h][d][s]
        #pragma unroll
        for (int mi = 0; mi < 4; mi++) {
            const int row0 = m0 + wm * 64 + mi * 16 + lg * 4;
            const int bb = row0 >> 11, ss0 = row0 & 2047;
            #pragma unroll
            for (int ni = 0; ni < 4; ni++) {
                s16x4 pk;
                pk[0] = f2bf(acc[mi][ni][0] + bcol[ni]);
                pk[1] = f2bf(acc[mi][ni][1] + bcol[ni]);
                pk[2] = f2bf(acc[mi][ni][2] + bcol[ni]);
                pk[3] = f2bf(acc[mi][ni][3] + bcol[ni]);
                *(s16x4*)(vt + (((size_t)(bb * NH_ + h)) * HD_ + ni * 16 + l16) * S_ + ss0) = pk;
            }
        }
    }
}

// ---------------------------------------------------------------------------
// O-proj GEMM, XCD-chunked 1-D grid (384 blocks).
// ---------------------------------------------------------------------------
__global__ __launch_bounds__(256)
void gemm_out(const short* __restrict__ A, const short* __restrict__ Bw,
              const float* __restrict__ bias, const float* __restrict__ res,
              float* __restrict__ o) {
    __shared__ __align__(16) short As[128 * 32];
    __shared__ __align__(16) short Bs[128 * 32];
    const int tid = threadIdx.x;
    const int w = tid >> 6, l = tid & 63;
    const int l16 = l & 15, lg = l >> 4;
    const int wm = w >> 1, wn = w & 1;
    const int flat = blockIdx.x;
    const int j = flat >> 3;
    const int m0 = ((flat & 7) * 8 + (j & 7)) * 128;
    const int n0 = (j >> 3) * 128;

    f32x4 acc[4][4];
    #pragma unroll
    for (int mi = 0; mi < 4; mi++)
        #pragma unroll
        for (int ni = 0; ni < 4; ni++)
            acc[mi][ni][0] = acc[mi][ni][1] = acc[mi][ni][2] = acc[mi][ni][3] = 0.f;

    for (int k0 = 0; k0 < K_; k0 += 32) {
        #pragma unroll
        for (int i = 0; i < 2; i++) {
            const int o_ = w * 2048 + i * 1024 + l * 16;
            const int row = o_ >> 6, colb = o_ & 63;
            const char* ga = (const char*)A  + (((size_t)(m0 + row)) * K_ + k0) * 2 + colb;
            const char* gb = (const char*)Bw + (((size_t)(n0 + row)) * K_ + k0) * 2 + colb;
            GLDS16(ga, (char*)As + w * 2048 + i * 1024);
            GLDS16(gb, (char*)Bs + w * 2048 + i * 1024);
        }
        __syncthreads();

        bf16x8 af[4], bfr[4];
        #pragma unroll
        for (int mi = 0; mi < 4; mi++)
            af[mi] = *(const bf16x8*)&As[(wm * 64 + mi * 16 + l16) * 32 + lg * 8];
        #pragma unroll
        for (int ni = 0; ni < 4; ni++)
            bfr[ni] = *(const bf16x8*)&Bs[(wn * 64 + ni * 16 + l16) * 32 + lg * 8];
        #pragma unroll
        for (int mi = 0; mi < 4; mi++)
            #pragma unroll
            for (int ni = 0; ni < 4; ni++)
                acc[mi][ni] = __builtin_amdgcn_mfma_f32_16x16x32_bf16(af[mi], bfr[ni], acc[mi][ni], 0, 0, 0);
        __syncthreads();
    }

    float bcol[4];
    #pragma unroll
    for (int ni = 0; ni < 4; ni++) bcol[ni] = bias[n0 + wn * 64 + ni * 16 + l16];
    #pragma unroll
    for (int mi = 0; mi < 4; mi++) {
        #pragma unroll
        for (int r = 0; r < 4; r++) {
            const int row = m0 + wm * 64 + mi * 16 + lg * 4 + r;
            #pragma unroll
            for (int ni = 0; ni < 4; ni++) {
                const int col = n0 + wn * 64 + ni * 16 + l16;
                o[(size_t)row * H_ + col] = acc[mi][ni][r] + bcol[ni] + res[(size_t)row * H_ + col];
            }
        }
    }
}

// ---------------------------------------------------------------------------
// MFMA flash attention: Q-block 128 = 8 waves x 16 q-rows, KV tile 64.
// 1-D grid, XCD-chunked: bid = qt*48 + bhid.  Since 48 % 8 == 0, all 16
// qt-blocks of one (b,h) share bid%8 -> same XCD -> its K/V (512KB) is
// fetched into ONE L2 (6 bh-pairs x 512KB = 3MB < 4MB per XCD) instead of
// being replicated across 8 (R20 FETCH showed 2.7x over-fetch).
// P round-trip: same-typed uint2 LDS + asm memory clobber + s_waitcnt
// lgkmcnt(0) (the R20-proven correct protocol).
// ---------------------------------------------------------------------------
__global__ __launch_bounds__(512)
void flash_attn_mfma(const short* __restrict__ q, const short* __restrict__ k,
                     const short* __restrict__ vt, const float* __restrict__ mask,
                     short* __restrict__ ctx) {
    const int bid = blockIdx.x;
    const int qt = bid / 48;               // 0..15
    const int bhid = bid % 48;             // 0..47; bid%8 == bhid%8 -> XCD-stable
    const int b = bhid / NH_, h = bhid % NH_;
    __shared__ __align__(16) short KsL[2][4096];   // [buf][64 s][128B] swz
    __shared__ __align__(16) short VtL[2][4096];   // [buf][64 d][128B] swz
    __shared__ __align__(16) uint2 PsP[128 * 16];  // [128 rows][16 uint2]
    const int tid = threadIdx.x;
    const int w = tid >> 6, l = tid & 63;
    const int l16 = l & 15, lg = l >> 4;

    const size_t bh = (size_t)(b * NH_ + h);
    bf16x8 qf0, qf1;
    {
        const size_t qr = (bh * S_ + (size_t)qt * 128 + w * 16 + l16) * HD_;
        qf0 = *(const bf16x8*)(q + qr + lg * 8);
        qf1 = *(const bf16x8*)(q + qr + 32 + lg * 8);
    }
    const size_t kbase  = bh * S_ * HD_;   // K  [s][d]
    const size_t vtbase = bh * HD_ * S_;   // Vt [d][s]

    bf16x8 ones;
    #pragma unroll
    for (int jj = 0; jj < 8; jj++) ones[jj] = (short)0x3F80;

    f32x4 oacc[4], lsum;
    #pragma unroll
    for (int i = 0; i < 4; i++) oacc[i][0] = oacc[i][1] = oacc[i][2] = oacc[i][3] = 0.f;
    lsum[0] = lsum[1] = lsum[2] = lsum[3] = 0.f;
    float m_reg = -3.0e38f;

    // staging: 512 threads x 16B = one full 8KB tile each for K and Vt
    const int srow = tid >> 3;             // 0..63
    const int sc0  = (tid & 7) * 16;       // byte col within 128B row
    const int wr0  = (srow << 7) + (sc0 ^ ((srow & 7) << 4));

    // P LDS geometry (uint2 units)
    const int prow = w * 16 + l16;         // this lane's P row (0..127)
    const int pu_base = prow * 16;

    bf16x8 nk, nv;
    #define LOADT(ct_) do {                                                        \
        nk = *(const bf16x8*)((const char*)(k  + kbase  + (size_t)((ct_) * 64 + srow) * HD_) + sc0); \
        nv = *(const bf16x8*)((const char*)(vt + vtbase + (size_t)srow * S_ + (ct_) * 64) + sc0);    \
    } while (0)
    #define WRITET(bu_) do {                                                       \
        *(bf16x8*)((char*)KsL[bu_] + wr0) = nk;                                    \
        *(bf16x8*)((char*)VtL[bu_] + wr0) = nv;                                    \
    } while (0)

    LOADT(0);
    WRITET(0);
    __syncthreads();

    int cbuf = 0;
    for (int ct = 0; ct < S_ / 64; ct++) {
        if (ct + 1 < S_ / 64) LOADT(ct + 1);   // issue early: hide under compute

        // ---- S^T = mfma(K, Q) with C initialized to the (log2-scaled) mask ----
        f32x4 sacc[4];
        #pragma unroll
        for (int n = 0; n < 4; n++) {
            float4 mk = *(const float4*)(mask + (size_t)b * S_ + ct * 64 + n * 16 + lg * 4);
            sacc[n][0] = mk.x; sacc[n][1] = mk.y; sacc[n][2] = mk.z; sacc[n][3] = mk.w;
        }
        __builtin_amdgcn_s_setprio(1);
        #pragma unroll
        for (int n = 0; n < 4; n++) {
            bf16x8 kb0 = *LDSRD(KsL[cbuf], n * 16 + l16, lg * 16);
            bf16x8 kb1 = *LDSRD(KsL[cbuf], n * 16 + l16, 64 + lg * 16);
            sacc[n] = __builtin_amdgcn_mfma_f32_16x16x32_bf16(kb0, qf0, sacc[n], 0, 0, 0);
            sacc[n] = __builtin_amdgcn_mfma_f32_16x16x32_bf16(kb1, qf1, sacc[n], 0, 0, 0);
        }
        __builtin_amdgcn_s_setprio(0);

        // ---- lane-local max for q-row l16 ----
        float x0 = fmaxf(fmaxf(sacc[0][0], sacc[0][1]), fmaxf(sacc[0][2], sacc[0][3]));
        float x1 = fmaxf(fmaxf(sacc[1][0], sacc[1][1]), fmaxf(sacc[1][2], sacc[1][3]));
        float x2 = fmaxf(fmaxf(sacc[2][0], sacc[2][1]), fmaxf(sacc[2][2], sacc[2][3]));
        float x3 = fmaxf(fmaxf(sacc[3][0], sacc[3][1]), fmaxf(sacc[3][2], sacc[3][3]));
        float pmax = fmaxf(fmaxf(x0, x1), fmaxf(x2, x3));
        pmax = fmaxf(pmax, __shfl_xor(pmax, 16));
        pmax = fmaxf(pmax, __shfl_xor(pmax, 32));

        // ---- defer-max rescale (T13) ----
        if (!__all(pmax - m_reg <= 8.f)) {
            const float mn = fmaxf(m_reg, pmax);
            const float corr = __builtin_amdgcn_exp2f(m_reg - mn);
            m_reg = mn;
            float corr4[4];
            #pragma unroll
            for (int r = 0; r < 4; r++) corr4[r] = __shfl(corr, lg * 4 + r);
            #pragma unroll
            for (int nd = 0; nd < 4; nd++)
                #pragma unroll
                for (int r = 0; r < 4; r++) oacc[nd][r] *= corr4[r];
            #pragma unroll
            for (int r = 0; r < 4; r++) lsum[r] *= corr4[r];
        }

        // ---- P = exp2(s - m): pack and store (same-typed uint2 LDS) ----
        #pragma unroll
        for (int n = 0; n < 4; n++) {
            uint2 pk;
            pk.x = cvt_pk_bf16(__builtin_amdgcn_exp2f(sacc[n][0] - m_reg),
                               __builtin_amdgcn_exp2f(sacc[n][1] - m_reg));
            pk.y = cvt_pk_bf16(__builtin_amdgcn_exp2f(sacc[n][2] - m_reg),
                               __builtin_amdgcn_exp2f(sacc[n][3] - m_reg));
            PsP[pu_base + ((4 * n + lg) ^ l16)] = pk;
        }
        // Compile-time fence (no elision/hoist across) ...
        asm volatile("" ::: "memory");
        // ... plus HARDWARE fence: drain the P ds_writes before any P ds_read
        // issues (LDS write->read of same bytes is not otherwise ordered).
        asm volatile("s_waitcnt lgkmcnt(0)" ::: "memory");
        __builtin_amdgcn_sched_barrier(0);

        // ---- rebuild PV A-fragments (same-typed uint2 reads) ----
        uint2 r0 = PsP[pu_base + ((2 * lg)     ^ l16)];
        uint2 r1 = PsP[pu_base + ((2 * lg + 1) ^ l16)];
        uint2 r2 = PsP[pu_base + ((8 + 2 * lg)     ^ l16)];
        uint2 r3 = PsP[pu_base + ((8 + 2 * lg + 1) ^ l16)];
        asm volatile("" ::: "memory");
        __builtin_amdgcn_sched_barrier(0);
        union U8 { unsigned u[4]; bf16x8 v; } A0, A1;
        A0.u[0] = r0.x; A0.u[1] = r0.y; A0.u[2] = r1.x; A0.u[3] = r1.y;
        A1.u[0] = r2.x; A1.u[1] = r2.y; A1.u[2] = r3.x; A1.u[3] = r3.y;
        bf16x8 pa0 = A0.v, pa1 = A1.v;

        // ---- O += P V ; l += P 1 ----
        __builtin_amdgcn_s_setprio(1);
        lsum = __builtin_amdgcn_mfma_f32_16x16x32_bf16(pa0, ones, lsum, 0, 0, 0);
        lsum = __builtin_amdgcn_mfma_f32_16x16x32_bf16(pa1, ones, lsum, 0, 0, 0);
        #pragma unroll
        for (int nd = 0; nd < 4; nd++) {
            bf16x8 vb0 = *LDSRD(VtL[cbuf], nd * 16 + l16, lg * 16);
            bf16x8 vb1 = *LDSRD(VtL[cbuf], nd * 16 + l16, 64 + lg * 16);
            oacc[nd] = __builtin_amdgcn_mfma_f32_16x16x32_bf16(pa0, vb0, oacc[nd], 0, 0, 0);
            oacc[nd] = __builtin_amdgcn_mfma_f32_16x16x32_bf16(pa1, vb1, oacc[nd], 0, 0, 0);
        }
        __builtin_amdgcn_s_setprio(0);

        // ---- write-late: staged regs -> other buffer ----
        if (ct + 1 < S_ / 64) WRITET(cbuf ^ 1);
        __syncthreads();   // publish next buffer / protect K,V reads
        cbuf ^= 1;
    }
    #undef LOADT
    #undef WRITET

    // ---- normalize + write ctx bf16 [M][H] (lsum already in O-layout) ----
    #pragma unroll
    for (int r = 0; r < 4; r++) {
        const float inv = 1.f / lsum[r];
        const size_t row = (size_t)(b * S_ + qt * 128 + w * 16 + lg * 4 + r);
        #pragma unroll
        for (int nd = 0; nd < 4; nd++)
            ctx[row * H_ + h * HD_ + nd * 16 + l16] = f2bf(oacc[nd][r] * inv);
    }
}

// ---------------------------------------------------------------------------
// LayerNorm over last dim (768). One block (256 thr) per row.
// ---------------------------------------------------------------------------
__global__ __launch_bounds__(256)
void layernorm_k(const float* __restrict__ hin, const float* __restrict__ g,
                 const float* __restrict__ beta, float* __restrict__ out) {
    const int row = blockIdx.x;
    const int tid = threadIdx.x;
    const float* x = hin + (size_t)row * H_;
    __shared__ float sm[4];

    float v0 = x[tid], v1 = x[tid + 256], v2 = x[tid + 512];
    float s = v0 + v1 + v2;
    #pragma unroll
    for (int o = 32; o > 0; o >>= 1) s += __shfl_xor(s, o);
    if ((tid & 63) == 0) sm[tid >> 6] = s;
    __syncthreads();
    float mu = (sm[0] + sm[1] + sm[2] + sm[3]) * (1.f / 768.f);

    float d0 = v0 - mu, d1 = v1 - mu, d2 = v2 - mu;
    float ss = d0*d0 + d1*d1 + d2*d2;
    #pragma unroll
    for (int o = 32; o > 0; o >>= 1) ss += __shfl_xor(ss, o);
    __syncthreads();
    if ((tid & 63) == 0) sm[tid >> 6] = ss;
    __syncthreads();
    float var = (sm[0] + sm[1] + sm[2] + sm[3]) * (1.f / 768.f);
    float sc = rsqrtf(var + 1e-12f);

    float* y = out + (size_t)row * H_;
    y[tid]       = d0 * sc * g[tid]       + beta[tid];
    y[tid + 256] = d1 * sc * g[tid + 256] + beta[tid + 256];
    y[tid + 512] = d2 * sc * g[tid + 512] + beta[tid + 512];
}

// ---------------------------------------------------------------------------
extern "C" void kernel_launch(void* const* d_in, const int* in_sizes, int n_in,
                              void* d_out, int out_size, void* d_ws, size_t ws_size,
                              hipStream_t stream) {
    const float* hs   = (const float*)d_in[0];
    const float* mask = (const float*)d_in[1];
    const float* Wq   = (const float*)d_in[2];
    const float* bq   = (const float*)d_in[3];
    const float* Wk   = (const float*)d_in[4];
    const float* bk   = (const float*)d_in[5];
    const float* Wv   = (const float*)d_in[6];
    const float* bv   = (const float*)d_in[7];
    const float* Wo   = (const float*)d_in[8];
    const float* bo   = (const float*)d_in[9];
    const float* ln_g = (const float*)d_in[10];
    const float* ln_b = (const float*)d_in[11];
    float* out = (float*)d_out;

    const size_t MH = (size_t)M_ * H_;
    const size_t HH = (size_t)H_ * H_;
    short* hsbf = (short*)d_ws;       // [M][768] bf16
    short* wqbf = hsbf + MH;          // [2304][768] consecutive Wq,Wk,Wv
    short* wkbf = wqbf + HH;
    short* wvbf = wkbf + HH;
    short* wobf = wvbf + HH;
    short* qbf  = wobf + HH;          // [b][h][s][d] bf16; q,k consecutive
    short* kbf  = qbf + MH;
    short* vtb  = kbf + MH;           // [b][h][d][s] (written by gemm_qkv)
    short* cbf  = vtb + MH;           // ctx bf16 [M][768]
    float* hb   = (float*)(cbf + MH); // fp32 [M][768]
    float* msk2 = hb + MH;            // mask * log2e (8192 fp32)

    cvt6<<<dim3(256, 6), 256, 0, stream>>>(hs, Wq, Wk, Wv, Wo, mask,
                                           hsbf, wqbf, wkbf, wvbf, wobf, msk2);

    gemm_qkv<<<dim3(1152), 256, 0, stream>>>(hsbf, wqbf, bq, bk, bv, qbf, vtb);

    flash_attn_mfma<<<dim3(768), 512, 0, stream>>>(qbf, kbf, vtb, msk2, cbf);

    gemm_out<<<dim3(384), 256, 0, stream>>>(cbf, wobf, bo, hs, hb);

    layernorm_k<<<M_, 256, 0, stream>>>(hb, ln_g, ln_b, out);
}

// Round 22
// 185.253 us; speedup vs baseline: 1.1556x; 1.0006x over previous
//
#include <hip/hip_runtime.h>
#include <math.h>

#define B_  4
#define S_  2048
#define H_  768
#define NH_ 12
#define HD_ 64
#define M_  (B_*S_)   // 8192
#define K_  768
#define LOG2E 1.44269504088896340736f

using bf16x8 = __attribute__((ext_vector_type(8))) short;
using s16x4  = __attribute__((ext_vector_type(4))) short;
using f32x4  = __attribute__((ext_vector_type(4))) float;

__device__ inline short f2bf(float f) {
    union { float f; unsigned u; } v{f};
    unsigned r = (v.u + 0x7FFF + ((v.u >> 16) & 1)) >> 16;   // RNE
    return (short)r;
}

__device__ inline unsigned cvt_pk_bf16(float lo, float hi) {
    unsigned r;
    asm("v_cvt_pk_bf16_f32 %0, %1, %2" : "=v"(r) : "v"(lo), "v"(hi));
    return r;
}

#define GLDS16(g, l) __builtin_amdgcn_global_load_lds( \
    (const __attribute__((address_space(1))) void*)(g), \
    (__attribute__((address_space(3))) void*)(l), 16, 0, 0)

// swizzled LDS read: linear [R][128B] tile, byte ^= ((row&7)<<4)
__device__ inline const bf16x8* LDSRD(const short* base, int row, int colByte) {
    return (const bf16x8*)((const char*)base + ((row << 7) + (colByte ^ ((row & 7) << 4))));
}

// ---------------------------------------------------------------------------
// fp32 -> bf16 conversion (regions 0-4: hs, Wq, Wk, Wv, Wo) + mask*log2e (5)
// ---------------------------------------------------------------------------
__global__ __launch_bounds__(256)
void cvt6(const float* __restrict__ s0, const float* __restrict__ s1,
          const float* __restrict__ s2, const float* __restrict__ s3,
          const float* __restrict__ s4, const float* __restrict__ msk,
          short* __restrict__ d0, short* __restrict__ d1,
          short* __restrict__ d2, short* __restrict__ d3,
          short* __restrict__ d4, float* __restrict__ msk2) {
    const int r = blockIdx.y;
    if (r == 5) {
        for (int i = blockIdx.x * blockDim.x + threadIdx.x; i < (B_ * S_) / 4;
             i += gridDim.x * blockDim.x) {
            float4 v = ((const float4*)msk)[i];
            v.x *= LOG2E; v.y *= LOG2E; v.z *= LOG2E; v.w *= LOG2E;
            ((float4*)msk2)[i] = v;
        }
        return;
    }
    const float* s = r == 0 ? s0 : r == 1 ? s1 : r == 2 ? s2 : r == 3 ? s3 : s4;
    short* d      = r == 0 ? d0 : r == 1 ? d1 : r == 2 ? d2 : r == 3 ? d3 : d4;
    const int n4  = (r == 0 ? M_ * H_ : H_ * H_) >> 2;
    for (int i = blockIdx.x * blockDim.x + threadIdx.x; i < n4; i += gridDim.x * blockDim.x) {
        float4 v = ((const float4*)s)[i];
        s16x4 o;
        o[0] = f2bf(v.x); o[1] = f2bf(v.y); o[2] = f2bf(v.z); o[3] = f2bf(v.w);
        ((s16x4*)d)[i] = o;
    }
}

// ---------------------------------------------------------------------------
// Fused QKV GEMM, XCD-chunked 1-D grid (1152 blocks), BK=64 dual-panel:
// two independent 32-wide panels per sync-pair (half the barriers of BK=32,
// identical per-panel layout/staging/fragment addressing as the BK=32 ver).
// Q/K -> bf16 head-major [b][h][s][d]; V -> transposed [b][h][d][s].
// ---------------------------------------------------------------------------
__global__ __launch_bounds__(256)
void gemm_qkv(const short* __restrict__ A, const short* __restrict__ Bw,
              const float* __restrict__ bq, const float* __restrict__ bk,
              const float* __restrict__ bv, short* __restrict__ obase,
              short* __restrict__ vt) {
    __shared__ __align__(16) short As[2][128 * 32];
    __shared__ __align__(16) short Bs[2][128 * 32];
    const int tid = threadIdx.x;
    const int w = tid >> 6, l = tid & 63;
    const int l16 = l & 15, lg = l >> 4;
    const int wm = w >> 1, wn = w & 1;
    const int flat = blockIdx.x;
    const int j = flat >> 3;
    const int mt = (flat & 7) * 8 + (j & 7);
    const int nty = j >> 3;                    // 0..17
    const int m0 = mt * 128, n0 = nty * 128;
    const int which = nty / 6;
    const float* bias = which == 0 ? bq : which == 1 ? bk : bv;
    const float scale = which == 0 ? 0.125f * LOG2E : 1.0f;

    f32x4 acc[4][4];
    #pragma unroll
    for (int mi = 0; mi < 4; mi++)
        #pragma unroll
        for (int ni = 0; ni < 4; ni++)
            acc[mi][ni][0] = acc[mi][ni][1] = acc[mi][ni][2] = acc[mi][ni][3] = 0.f;

    for (int k0 = 0; k0 < K_; k0 += 64) {
        #pragma unroll
        for (int p = 0; p < 2; p++) {
            const int kp = k0 + p * 32;
            #pragma unroll
            for (int i = 0; i < 2; i++) {
                const int o = w * 2048 + i * 1024 + l * 16;
                const int row = o >> 6, colb = o & 63;
                const char* ga = (const char*)A  + (((size_t)(m0 + row)) * K_ + kp) * 2 + colb;
                const char* gb = (const char*)Bw + (((size_t)(n0 + row)) * K_ + kp) * 2 + colb;
                GLDS16(ga, (char*)As[p] + w * 2048 + i * 1024);
                GLDS16(gb, (char*)Bs[p] + w * 2048 + i * 1024);
            }
        }
        __syncthreads();

        #pragma unroll
        for (int p = 0; p < 2; p++) {
            bf16x8 af[4], bfr[4];
            #pragma unroll
            for (int mi = 0; mi < 4; mi++)
                af[mi] = *(const bf16x8*)&As[p][(wm * 64 + mi * 16 + l16) * 32 + lg * 8];
            #pragma unroll
            for (int ni = 0; ni < 4; ni++)
                bfr[ni] = *(const bf16x8*)&Bs[p][(wn * 64 + ni * 16 + l16) * 32 + lg * 8];
            #pragma unroll
            for (int mi = 0; mi < 4; mi++)
                #pragma unroll
                for (int ni = 0; ni < 4; ni++)
                    acc[mi][ni] = __builtin_amdgcn_mfma_f32_16x16x32_bf16(af[mi], bfr[ni], acc[mi][ni], 0, 0, 0);
        }
        __syncthreads();
    }

    const int ncol0 = (nty % 6) * 128;
    float bcol[4];
    #pragma unroll
    for (int ni = 0; ni < 4; ni++) bcol[ni] = bias[ncol0 + wn * 64 + ni * 16 + l16];

    const int h = (nty % 6) * 2 + wn;   // wave's 64-col span == one head
    if (which < 2) {
        short* obf = obase + (size_t)which * M_ * H_;
        #pragma unroll
        for (int mi = 0; mi < 4; mi++) {
            #pragma unroll
            for (int r = 0; r < 4; r++) {
                const int row = m0 + wm * 64 + mi * 16 + lg * 4 + r;
                const int bb = row >> 11, ss = row & 2047;
                const size_t base = (((size_t)(bb * NH_ + h)) * S_ + ss) * HD_;
                #pragma unroll
                for (int ni = 0; ni < 4; ni++)
                    obf[base + ni * 16 + l16] = f2bf((acc[mi][ni][r] + bcol[ni]) * scale);
            }
        }
    } else {
        // V: transposed store [b][h][d][s]
        #pragma unroll
        for (int mi = 0; mi < 4; mi++) {
            const int row0 = m0 + wm * 64 + mi * 16 + lg * 4;
            const int bb = row0 >> 11, ss0 = row0 & 2047;
            #pragma unroll
            for (int ni = 0; ni < 4; ni++) {
                s16x4 pk;
                pk[0] = f2bf(acc[mi][ni][0] + bcol[ni]);
                pk[1] = f2bf(acc[mi][ni][1] + bcol[ni]);
                pk[2] = f2bf(acc[mi][ni][2] + bcol[ni]);
                pk[3] = f2bf(acc[mi][ni][3] + bcol[ni]);
                *(s16x4*)(vt + (((size_t)(bb * NH_ + h)) * HD_ + ni * 16 + l16) * S_ + ss0) = pk;
            }
        }
    }
}

// ---------------------------------------------------------------------------
// O-proj GEMM, XCD-chunked 1-D grid (384 blocks), BK=64 dual-panel.
// ---------------------------------------------------------------------------
__global__ __launch_bounds__(256)
void gemm_out(const short* __restrict__ A, const short* __restrict__ Bw,
              const float* __restrict__ bias, const float* __restrict__ res,
              float* __restrict__ o) {
    __shared__ __align__(16) short As[2][128 * 32];
    __shared__ __align__(16) short Bs[2][128 * 32];
    const int tid = threadIdx.x;
    const int w = tid >> 6, l = tid & 63;
    const int l16 = l & 15, lg = l >> 4;
    const int wm = w >> 1, wn = w & 1;
    const int flat = blockIdx.x;
    const int j = flat >> 3;
    const int m0 = ((flat & 7) * 8 + (j & 7)) * 128;
    const int n0 = (j >> 3) * 128;

    f32x4 acc[4][4];
    #pragma unroll
    for (int mi = 0; mi < 4; mi++)
        #pragma unroll
        for (int ni = 0; ni < 4; ni++)
            acc[mi][ni][0] = acc[mi][ni][1] = acc[mi][ni][2] = acc[mi][ni][3] = 0.f;

    for (int k0 = 0; k0 < K_; k0 += 64) {
        #pragma unroll
        for (int p = 0; p < 2; p++) {
            const int kp = k0 + p * 32;
            #pragma unroll
            for (int i = 0; i < 2; i++) {
                const int o_ = w * 2048 + i * 1024 + l * 16;
                const int row = o_ >> 6, colb = o_ & 63;
                const char* ga = (const char*)A  + (((size_t)(m0 + row)) * K_ + kp) * 2 + colb;
                const char* gb = (const char*)Bw + (((size_t)(n0 + row)) * K_ + kp) * 2 + colb;
                GLDS16(ga, (char*)As[p] + w * 2048 + i * 1024);
                GLDS16(gb, (char*)Bs[p] + w * 2048 + i * 1024);
            }
        }
        __syncthreads();

        #pragma unroll
        for (int p = 0; p < 2; p++) {
            bf16x8 af[4], bfr[4];
            #pragma unroll
            for (int mi = 0; mi < 4; mi++)
                af[mi] = *(const bf16x8*)&As[p][(wm * 64 + mi * 16 + l16) * 32 + lg * 8];
            #pragma unroll
            for (int ni = 0; ni < 4; ni++)
                bfr[ni] = *(const bf16x8*)&Bs[p][(wn * 64 + ni * 16 + l16) * 32 + lg * 8];
            #pragma unroll
            for (int mi = 0; mi < 4; mi++)
                #pragma unroll
                for (int ni = 0; ni < 4; ni++)
                    acc[mi][ni] = __builtin_amdgcn_mfma_f32_16x16x32_bf16(af[mi], bfr[ni], acc[mi][ni], 0, 0, 0);
        }
        __syncthreads();
    }

    float bcol[4];
    #pragma unroll
    for (int ni = 0; ni < 4; ni++) bcol[ni] = bias[n0 + wn * 64 + ni * 16 + l16];
    #pragma unroll
    for (int mi = 0; mi < 4; mi++) {
        #pragma unroll
        for (int r = 0; r < 4; r++) {
            const int row = m0 + wm * 64 + mi * 16 + lg * 4 + r;
            #pragma unroll
            for (int ni = 0; ni < 4; ni++) {
                const int col = n0 + wn * 64 + ni * 16 + l16;
                o[(size_t)row * H_ + col] = acc[mi][ni][r] + bcol[ni] + res[(size_t)row * H_ + col];
            }
        }
    }
}

// ---------------------------------------------------------------------------
// MFMA flash attention (UNCHANGED from R21 passing version): Q-block 128 =
// 8 waves x 16 q-rows, KV tile 64, XCD-chunked 1-D grid (bid = qt*48+bhid),
// P round-trip: same-typed uint2 LDS + asm memory clobber + s_waitcnt
// lgkmcnt(0) (the R20-proven correct protocol).
// ---------------------------------------------------------------------------
__global__ __launch_bounds__(512)
void flash_attn_mfma(const short* __restrict__ q, const short* __restrict__ k,
                     const short* __restrict__ vt, const float* __restrict__ mask,
                     short* __restrict__ ctx) {
    const int bid = blockIdx.x;
    const int qt = bid / 48;               // 0..15
    const int bhid = bid % 48;             // 0..47; bid%8 == bhid%8 -> XCD-stable
    const int b = bhid / NH_, h = bhid % NH_;
    __shared__ __align__(16) short KsL[2][4096];   // [buf][64 s][128B] swz
    __shared__ __align__(16) short VtL[2][4096];   // [buf][64 d][128B] swz
    __shared__ __align__(16) uint2 PsP[128 * 16];  // [128 rows][16 uint2]
    const int tid = threadIdx.x;
    const int w = tid >> 6, l = tid & 63;
    const int l16 = l & 15, lg = l >> 4;

    const size_t bh = (size_t)(b * NH_ + h);
    bf16x8 qf0, qf1;
    {
        const size_t qr = (bh * S_ + (size_t)qt * 128 + w * 16 + l16) * HD_;
        qf0 = *(const bf16x8*)(q + qr + lg * 8);
        qf1 = *(const bf16x8*)(q + qr + 32 + lg * 8);
    }
    const size_t kbase  = bh * S_ * HD_;   // K  [s][d]
    const size_t vtbase = bh * HD_ * S_;   // Vt [d][s]

    bf16x8 ones;
    #pragma unroll
    for (int jj = 0; jj < 8; jj++) ones[jj] = (short)0x3F80;

    f32x4 oacc[4], lsum;
    #pragma unroll
    for (int i = 0; i < 4; i++) oacc[i][0] = oacc[i][1] = oacc[i][2] = oacc[i][3] = 0.f;
    lsum[0] = lsum[1] = lsum[2] = lsum[3] = 0.f;
    float m_reg = -3.0e38f;

    // staging: 512 threads x 16B = one full 8KB tile each for K and Vt
    const int srow = tid >> 3;             // 0..63
    const int sc0  = (tid & 7) * 16;       // byte col within 128B row
    const int wr0  = (srow << 7) + (sc0 ^ ((srow & 7) << 4));

    // P LDS geometry (uint2 units)
    const int prow = w * 16 + l16;         // this lane's P row (0..127)
    const int pu_base = prow * 16;

    bf16x8 nk, nv;
    #define LOADT(ct_) do {                                                        \
        nk = *(const bf16x8*)((const char*)(k  + kbase  + (size_t)((ct_) * 64 + srow) * HD_) + sc0); \
        nv = *(const bf16x8*)((const char*)(vt + vtbase + (size_t)srow * S_ + (ct_) * 64) + sc0);    \
    } while (0)
    #define WRITET(bu_) do {                                                       \
        *(bf16x8*)((char*)KsL[bu_] + wr0) = nk;                                    \
        *(bf16x8*)((char*)VtL[bu_] + wr0) = nv;                                    \
    } while (0)

    LOADT(0);
    WRITET(0);
    __syncthreads();

    int cbuf = 0;
    for (int ct = 0; ct < S_ / 64; ct++) {
        if (ct + 1 < S_ / 64) LOADT(ct + 1);   // issue early: hide under compute

        // ---- S^T = mfma(K, Q) with C initialized to the (log2-scaled) mask ----
        f32x4 sacc[4];
        #pragma unroll
        for (int n = 0; n < 4; n++) {
            float4 mk = *(const float4*)(mask + (size_t)b * S_ + ct * 64 + n * 16 + lg * 4);
            sacc[n][0] = mk.x; sacc[n][1] = mk.y; sacc[n][2] = mk.z; sacc[n][3] = mk.w;
        }
        __builtin_amdgcn_s_setprio(1);
        #pragma unroll
        for (int n = 0; n < 4; n++) {
            bf16x8 kb0 = *LDSRD(KsL[cbuf], n * 16 + l16, lg * 16);
            bf16x8 kb1 = *LDSRD(KsL[cbuf], n * 16 + l16, 64 + lg * 16);
            sacc[n] = __builtin_amdgcn_mfma_f32_16x16x32_bf16(kb0, qf0, sacc[n], 0, 0, 0);
            sacc[n] = __builtin_amdgcn_mfma_f32_16x16x32_bf16(kb1, qf1, sacc[n], 0, 0, 0);
        }
        __builtin_amdgcn_s_setprio(0);

        // ---- lane-local max for q-row l16 ----
        float x0 = fmaxf(fmaxf(sacc[0][0], sacc[0][1]), fmaxf(sacc[0][2], sacc[0][3]));
        float x1 = fmaxf(fmaxf(sacc[1][0], sacc[1][1]), fmaxf(sacc[1][2], sacc[1][3]));
        float x2 = fmaxf(fmaxf(sacc[2][0], sacc[2][1]), fmaxf(sacc[2][2], sacc[2][3]));
        float x3 = fmaxf(fmaxf(sacc[3][0], sacc[3][1]), fmaxf(sacc[3][2], sacc[3][3]));
        float pmax = fmaxf(fmaxf(x0, x1), fmaxf(x2, x3));
        pmax = fmaxf(pmax, __shfl_xor(pmax, 16));
        pmax = fmaxf(pmax, __shfl_xor(pmax, 32));

        // ---- defer-max rescale (T13) ----
        if (!__all(pmax - m_reg <= 8.f)) {
            const float mn = fmaxf(m_reg, pmax);
            const float corr = __builtin_amdgcn_exp2f(m_reg - mn);
            m_reg = mn;
            float corr4[4];
            #pragma unroll
            for (int r = 0; r < 4; r++) corr4[r] = __shfl(corr, lg * 4 + r);
            #pragma unroll
            for (int nd = 0; nd < 4; nd++)
                #pragma unroll
                for (int r = 0; r < 4; r++) oacc[nd][r] *= corr4[r];
            #pragma unroll
            for (int r = 0; r < 4; r++) lsum[r] *= corr4[r];
        }

        // ---- P = exp2(s - m): pack and store (same-typed uint2 LDS) ----
        #pragma unroll
        for (int n = 0; n < 4; n++) {
            uint2 pk;
            pk.x = cvt_pk_bf16(__builtin_amdgcn_exp2f(sacc[n][0] - m_reg),
                               __builtin_amdgcn_exp2f(sacc[n][1] - m_reg));
            pk.y = cvt_pk_bf16(__builtin_amdgcn_exp2f(sacc[n][2] - m_reg),
                               __builtin_amdgcn_exp2f(sacc[n][3] - m_reg));
            PsP[pu_base + ((4 * n + lg) ^ l16)] = pk;
        }
        // Compile-time fence (no elision/hoist across) ...
        asm volatile("" ::: "memory");
        // ... plus HARDWARE fence: drain the P ds_writes before any P ds_read
        // issues (LDS write->read of same bytes is not otherwise ordered).
        asm volatile("s_waitcnt lgkmcnt(0)" ::: "memory");
        __builtin_amdgcn_sched_barrier(0);

        // ---- rebuild PV A-fragments (same-typed uint2 reads) ----
        uint2 r0 = PsP[pu_base + ((2 * lg)     ^ l16)];
        uint2 r1 = PsP[pu_base + ((2 * lg + 1) ^ l16)];
        uint2 r2 = PsP[pu_base + ((8 + 2 * lg)     ^ l16)];
        uint2 r3 = PsP[pu_base + ((8 + 2 * lg + 1) ^ l16)];
        asm volatile("" ::: "memory");
        __builtin_amdgcn_sched_barrier(0);
        union U8 { unsigned u[4]; bf16x8 v; } A0, A1;
        A0.u[0] = r0.x; A0.u[1] = r0.y; A0.u[2] = r1.x; A0.u[3] = r1.y;
        A1.u[0] = r2.x; A1.u[1] = r2.y; A1.u[2] = r3.x; A1.u[3] = r3.y;
        bf16x8 pa0 = A0.v, pa1 = A1.v;

        // ---- O += P V ; l += P 1 ----
        __builtin_amdgcn_s_setprio(1);
        lsum = __builtin_amdgcn_mfma_f32_16x16x32_bf16(pa0, ones, lsum, 0, 0, 0);
        lsum = __builtin_amdgcn_mfma_f32_16x16x32_bf16(pa1, ones, lsum, 0, 0, 0);
        #pragma unroll
        for (int nd = 0; nd < 4; nd++) {
            bf16x8 vb0 = *LDSRD(VtL[cbuf], nd * 16 + l16, lg * 16);
            bf16x8 vb1 = *LDSRD(VtL[cbuf], nd * 16 + l16, 64 + lg * 16);
            oacc[nd] = __builtin_amdgcn_mfma_f32_16x16x32_bf16(pa0, vb0, oacc[nd], 0, 0, 0);
            oacc[nd] = __builtin_amdgcn_mfma_f32_16x16x32_bf16(pa1, vb1, oacc[nd], 0, 0, 0);
        }
        __builtin_amdgcn_s_setprio(0);

        // ---- write-late: staged regs -> other buffer ----
        if (ct + 1 < S_ / 64) WRITET(cbuf ^ 1);
        __syncthreads();   // publish next buffer / protect K,V reads
        cbuf ^= 1;
    }
    #undef LOADT
    #undef WRITET

    // ---- normalize + write ctx bf16 [M][H] (lsum already in O-layout) ----
    #pragma unroll
    for (int r = 0; r < 4; r++) {
        const float inv = 1.f / lsum[r];
        const size_t row = (size_t)(b * S_ + qt * 128 + w * 16 + lg * 4 + r);
        #pragma unroll
        for (int nd = 0; nd < 4; nd++)
            ctx[row * H_ + h * HD_ + nd * 16 + l16] = f2bf(oacc[nd][r] * inv);
    }
}

// ---------------------------------------------------------------------------
// LayerNorm over last dim (768). One block (256 thr) per row.
// ---------------------------------------------------------------------------
__global__ __launch_bounds__(256)
void layernorm_k(const float* __restrict__ hin, const float* __restrict__ g,
                 const float* __restrict__ beta, float* __restrict__ out) {
    const int row = blockIdx.x;
    const int tid = threadIdx.x;
    const float* x = hin + (size_t)row * H_;
    __shared__ float sm[4];

    float v0 = x[tid], v1 = x[tid + 256], v2 = x[tid + 512];
    float s = v0 + v1 + v2;
    #pragma unroll
    for (int o = 32; o > 0; o >>= 1) s += __shfl_xor(s, o);
    if ((tid & 63) == 0) sm[tid >> 6] = s;
    __syncthreads();
    float mu = (sm[0] + sm[1] + sm[2] + sm[3]) * (1.f / 768.f);

    float d0 = v0 - mu, d1 = v1 - mu, d2 = v2 - mu;
    float ss = d0*d0 + d1*d1 + d2*d2;
    #pragma unroll
    for (int o = 32; o > 0; o >>= 1) ss += __shfl_xor(ss, o);
    __syncthreads();
    if ((tid & 63) == 0) sm[tid >> 6] = ss;
    __syncthreads();
    float var = (sm[0] + sm[1] + sm[2] + sm[3]) * (1.f / 768.f);
    float sc = rsqrtf(var + 1e-12f);

    float* y = out + (size_t)row * H_;
    y[tid]       = d0 * sc * g[tid]       + beta[tid];
    y[tid + 256] = d1 * sc * g[tid + 256] + beta[tid + 256];
    y[tid + 512] = d2 * sc * g[tid + 512] + beta[tid + 512];
}

// ---------------------------------------------------------------------------
extern "C" void kernel_launch(void* const* d_in, const int* in_sizes, int n_in,
                              void* d_out, int out_size, void* d_ws, size_t ws_size,
                              hipStream_t stream) {
    const float* hs   = (const float*)d_in[0];
    const float* mask = (const float*)d_in[1];
    const float* Wq   = (const float*)d_in[2];
    const float* bq   = (const float*)d_in[3];
    const float* Wk   = (const float*)d_in[4];
    const float* bk   = (const float*)d_in[5];
    const float* Wv   = (const float*)d_in[6];
    const float* bv   = (const float*)d_in[7];
    const float* Wo   = (const float*)d_in[8];
    const float* bo   = (const float*)d_in[9];
    const float* ln_g = (const float*)d_in[10];
    const float* ln_b = (const float*)d_in[11];
    float* out = (float*)d_out;

    const size_t MH = (size_t)M_ * H_;
    const size_t HH = (size_t)H_ * H_;
    short* hsbf = (short*)d_ws;       // [M][768] bf16
    short* wqbf = hsbf + MH;          // [2304][768] consecutive Wq,Wk,Wv
    short* wkbf = wqbf + HH;
    short* wvbf = wkbf + HH;
    short* wobf = wvbf + HH;
    short* qbf  = wobf + HH;          // [b][h][s][d] bf16; q,k consecutive
    short* kbf  = qbf + MH;
    short* vtb  = kbf + MH;           // [b][h][d][s] (written by gemm_qkv)
    short* cbf  = vtb + MH;           // ctx bf16 [M][768]
    float* hb   = (float*)(cbf + MH); // fp32 [M][768]
    float* msk2 = hb + MH;            // mask * log2e (8192 fp32)

    cvt6<<<dim3(256, 6), 256, 0, stream>>>(hs, Wq, Wk, Wv, Wo, mask,
                                           hsbf, wqbf, wkbf, wvbf, wobf, msk2);

    gemm_qkv<<<dim3(1152), 256, 0, stream>>>(hsbf, wqbf, bq, bk, bv, qbf, vtb);

    flash_attn_mfma<<<dim3(768), 512, 0, stream>>>(qbf, kbf, vtb, msk2, cbf);

    gemm_out<<<dim3(384), 256, 0, stream>>>(cbf, wobf, bo, hs, hb);

    layernorm_k<<<M_, 256, 0, stream>>>(hb, ln_g, ln_b, out);
}

// Round 23
// 184.737 us; speedup vs baseline: 1.1588x; 1.0028x over previous
//
#include <hip/hip_runtime.h>
#include <math.h>

#define B_  4
#define S_  2048
#define H_  768
#define NH_ 12
#define HD_ 64
#define M_  (B_*S_)   // 8192
#define K_  768
#define LOG2E 1.44269504088896340736f

using bf16x8 = __attribute__((ext_vector_type(8))) short;
using s16x4  = __attribute__((ext_vector_type(4))) short;
using f32x4  = __attribute__((ext_vector_type(4))) float;

__device__ inline short f2bf(float f) {
    union { float f; unsigned u; } v{f};
    unsigned r = (v.u + 0x7FFF + ((v.u >> 16) & 1)) >> 16;   // RNE
    return (short)r;
}

__device__ inline unsigned cvt_pk_bf16(float lo, float hi) {
    unsigned r;
    asm("v_cvt_pk_bf16_f32 %0, %1, %2" : "=v"(r) : "v"(lo), "v"(hi));
    return r;
}

#define GLDS16(g, l) __builtin_amdgcn_global_load_lds( \
    (const __attribute__((address_space(1))) void*)(g), \
    (__attribute__((address_space(3))) void*)(l), 16, 0, 0)

// swizzled LDS read: linear [R][128B] tile, byte ^= ((row&7)<<4)
__device__ inline const bf16x8* LDSRD(const short* base, int row, int colByte) {
    return (const bf16x8*)((const char*)base + ((row << 7) + (colByte ^ ((row & 7) << 4))));
}

// ---------------------------------------------------------------------------
// fp32 -> bf16 conversion (regions 0-4: hs, Wq, Wk, Wv, Wo) + mask*log2e (5)
// ---------------------------------------------------------------------------
__global__ __launch_bounds__(256)
void cvt6(const float* __restrict__ s0, const float* __restrict__ s1,
          const float* __restrict__ s2, const float* __restrict__ s3,
          const float* __restrict__ s4, const float* __restrict__ msk,
          short* __restrict__ d0, short* __restrict__ d1,
          short* __restrict__ d2, short* __restrict__ d3,
          short* __restrict__ d4, float* __restrict__ msk2) {
    const int r = blockIdx.y;
    if (r == 5) {
        for (int i = blockIdx.x * blockDim.x + threadIdx.x; i < (B_ * S_) / 4;
             i += gridDim.x * blockDim.x) {
            float4 v = ((const float4*)msk)[i];
            v.x *= LOG2E; v.y *= LOG2E; v.z *= LOG2E; v.w *= LOG2E;
            ((float4*)msk2)[i] = v;
        }
        return;
    }
    const float* s = r == 0 ? s0 : r == 1 ? s1 : r == 2 ? s2 : r == 3 ? s3 : s4;
    short* d      = r == 0 ? d0 : r == 1 ? d1 : r == 2 ? d2 : r == 3 ? d3 : d4;
    const int n4  = (r == 0 ? M_ * H_ : H_ * H_) >> 2;
    for (int i = blockIdx.x * blockDim.x + threadIdx.x; i < n4; i += gridDim.x * blockDim.x) {
        float4 v = ((const float4*)s)[i];
        s16x4 o;
        o[0] = f2bf(v.x); o[1] = f2bf(v.y); o[2] = f2bf(v.z); o[3] = f2bf(v.w);
        ((s16x4*)d)[i] = o;
    }
}

// ---------------------------------------------------------------------------
// Fused QKV GEMM, XCD-chunked 1-D grid (1152 blocks), BK=64 dual-panel.
// Q/K -> bf16 head-major [b][h][s][d]; V -> transposed [b][h][d][s].
// ---------------------------------------------------------------------------
__global__ __launch_bounds__(256)
void gemm_qkv(const short* __restrict__ A, const short* __restrict__ Bw,
              const float* __restrict__ bq, const float* __restrict__ bk,
              const float* __restrict__ bv, short* __restrict__ obase,
              short* __restrict__ vt) {
    __shared__ __align__(16) short As[2][128 * 32];
    __shared__ __align__(16) short Bs[2][128 * 32];
    const int tid = threadIdx.x;
    const int w = tid >> 6, l = tid & 63;
    const int l16 = l & 15, lg = l >> 4;
    const int wm = w >> 1, wn = w & 1;
    const int flat = blockIdx.x;
    const int j = flat >> 3;
    const int mt = (flat & 7) * 8 + (j & 7);
    const int nty = j >> 3;                    // 0..17
    const int m0 = mt * 128, n0 = nty * 128;
    const int which = nty / 6;
    const float* bias = which == 0 ? bq : which == 1 ? bk : bv;
    const float scale = which == 0 ? 0.125f * LOG2E : 1.0f;

    f32x4 acc[4][4];
    #pragma unroll
    for (int mi = 0; mi < 4; mi++)
        #pragma unroll
        for (int ni = 0; ni < 4; ni++)
            acc[mi][ni][0] = acc[mi][ni][1] = acc[mi][ni][2] = acc[mi][ni][3] = 0.f;

    for (int k0 = 0; k0 < K_; k0 += 64) {
        #pragma unroll
        for (int p = 0; p < 2; p++) {
            const int kp = k0 + p * 32;
            #pragma unroll
            for (int i = 0; i < 2; i++) {
                const int o = w * 2048 + i * 1024 + l * 16;
                const int row = o >> 6, colb = o & 63;
                const char* ga = (const char*)A  + (((size_t)(m0 + row)) * K_ + kp) * 2 + colb;
                const char* gb = (const char*)Bw + (((size_t)(n0 + row)) * K_ + kp) * 2 + colb;
                GLDS16(ga, (char*)As[p] + w * 2048 + i * 1024);
                GLDS16(gb, (char*)Bs[p] + w * 2048 + i * 1024);
            }
        }
        __syncthreads();

        #pragma unroll
        for (int p = 0; p < 2; p++) {
            bf16x8 af[4], bfr[4];
            #pragma unroll
            for (int mi = 0; mi < 4; mi++)
                af[mi] = *(const bf16x8*)&As[p][(wm * 64 + mi * 16 + l16) * 32 + lg * 8];
            #pragma unroll
            for (int ni = 0; ni < 4; ni++)
                bfr[ni] = *(const bf16x8*)&Bs[p][(wn * 64 + ni * 16 + l16) * 32 + lg * 8];
            #pragma unroll
            for (int mi = 0; mi < 4; mi++)
                #pragma unroll
                for (int ni = 0; ni < 4; ni++)
                    acc[mi][ni] = __builtin_amdgcn_mfma_f32_16x16x32_bf16(af[mi], bfr[ni], acc[mi][ni], 0, 0, 0);
        }
        __syncthreads();
    }

    const int ncol0 = (nty % 6) * 128;
    float bcol[4];
    #pragma unroll
    for (int ni = 0; ni < 4; ni++) bcol[ni] = bias[ncol0 + wn * 64 + ni * 16 + l16];

    const int h = (nty % 6) * 2 + wn;   // wave's 64-col span == one head
    if (which < 2) {
        short* obf = obase + (size_t)which * M_ * H_;
        #pragma unroll
        for (int mi = 0; mi < 4; mi++) {
            #pragma unroll
            for (int r = 0; r < 4; r++) {
                const int row = m0 + wm * 64 + mi * 16 + lg * 4 + r;
                const int bb = row >> 11, ss = row & 2047;
                const size_t base = (((size_t)(bb * NH_ + h)) * S_ + ss) * HD_;
                #pragma unroll
                for (int ni = 0; ni < 4; ni++)
                    obf[base + ni * 16 + l16] = f2bf((acc[mi][ni][r] + bcol[ni]) * scale);
            }
        }
    } else {
        // V: transposed store [b][h][d][s]
        #pragma unroll
        for (int mi = 0; mi < 4; mi++) {
            const int row0 = m0 + wm * 64 + mi * 16 + lg * 4;
            const int bb = row0 >> 11, ss0 = row0 & 2047;
            #pragma unroll
            for (int ni = 0; ni < 4; ni++) {
                s16x4 pk;
                pk[0] = f2bf(acc[mi][ni][0] + bcol[ni]);
                pk[1] = f2bf(acc[mi][ni][1] + bcol[ni]);
                pk[2] = f2bf(acc[mi][ni][2] + bcol[ni]);
                pk[3] = f2bf(acc[mi][ni][3] + bcol[ni]);
                *(s16x4*)(vt + (((size_t)(bb * NH_ + h)) * HD_ + ni * 16 + l16) * S_ + ss0) = pk;
            }
        }
    }
}

// ---------------------------------------------------------------------------
// O-proj GEMM, XCD-chunked 1-D grid (384 blocks), BK=64 dual-panel.
// ---------------------------------------------------------------------------
__global__ __launch_bounds__(256)
void gemm_out(const short* __restrict__ A, const short* __restrict__ Bw,
              const float* __restrict__ bias, const float* __restrict__ res,
              float* __restrict__ o) {
    __shared__ __align__(16) short As[2][128 * 32];
    __shared__ __align__(16) short Bs[2][128 * 32];
    const int tid = threadIdx.x;
    const int w = tid >> 6, l = tid & 63;
    const int l16 = l & 15, lg = l >> 4;
    const int wm = w >> 1, wn = w & 1;
    const int flat = blockIdx.x;
    const int j = flat >> 3;
    const int m0 = ((flat & 7) * 8 + (j & 7)) * 128;
    const int n0 = (j >> 3) * 128;

    f32x4 acc[4][4];
    #pragma unroll
    for (int mi = 0; mi < 4; mi++)
        #pragma unroll
        for (int ni = 0; ni < 4; ni++)
            acc[mi][ni][0] = acc[mi][ni][1] = acc[mi][ni][2] = acc[mi][ni][3] = 0.f;

    for (int k0 = 0; k0 < K_; k0 += 64) {
        #pragma unroll
        for (int p = 0; p < 2; p++) {
            const int kp = k0 + p * 32;
            #pragma unroll
            for (int i = 0; i < 2; i++) {
                const int o_ = w * 2048 + i * 1024 + l * 16;
                const int row = o_ >> 6, colb = o_ & 63;
                const char* ga = (const char*)A  + (((size_t)(m0 + row)) * K_ + kp) * 2 + colb;
                const char* gb = (const char*)Bw + (((size_t)(n0 + row)) * K_ + kp) * 2 + colb;
                GLDS16(ga, (char*)As[p] + w * 2048 + i * 1024);
                GLDS16(gb, (char*)Bs[p] + w * 2048 + i * 1024);
            }
        }
        __syncthreads();

        #pragma unroll
        for (int p = 0; p < 2; p++) {
            bf16x8 af[4], bfr[4];
            #pragma unroll
            for (int mi = 0; mi < 4; mi++)
                af[mi] = *(const bf16x8*)&As[p][(wm * 64 + mi * 16 + l16) * 32 + lg * 8];
            #pragma unroll
            for (int ni = 0; ni < 4; ni++)
                bfr[ni] = *(const bf16x8*)&Bs[p][(wn * 64 + ni * 16 + l16) * 32 + lg * 8];
            #pragma unroll
            for (int mi = 0; mi < 4; mi++)
                #pragma unroll
                for (int ni = 0; ni < 4; ni++)
                    acc[mi][ni] = __builtin_amdgcn_mfma_f32_16x16x32_bf16(af[mi], bfr[ni], acc[mi][ni], 0, 0, 0);
        }
        __syncthreads();
    }

    float bcol[4];
    #pragma unroll
    for (int ni = 0; ni < 4; ni++) bcol[ni] = bias[n0 + wn * 64 + ni * 16 + l16];
    #pragma unroll
    for (int mi = 0; mi < 4; mi++) {
        #pragma unroll
        for (int r = 0; r < 4; r++) {
            const int row = m0 + wm * 64 + mi * 16 + lg * 4 + r;
            #pragma unroll
            for (int ni = 0; ni < 4; ni++) {
                const int col = n0 + wn * 64 + ni * 16 + l16;
                o[(size_t)row * H_ + col] = acc[mi][ni][r] + bcol[ni] + res[(size_t)row * H_ + col];
            }
        }
    }
}

// ---------------------------------------------------------------------------
// MFMA flash attention: Q-block 128 = 8 waves x 16 q-rows, KV tile 64,
// XCD-chunked 1-D grid (bid = qt*48+bhid).  P protocol: same-typed uint2
// LDS + asm memory clobber + s_waitcnt lgkmcnt(0) (R20-proven).
// R22 change: WRITET hoisted ABOVE the PV MFMA cluster so the 4 staging
// ds_writes drain under PV compute instead of at the barrier.  Safe:
// buffer cbuf^1 is read by nobody during tile ct (prior barrier retired
// those reads), and WRITET stays after the P-path drain.
// ---------------------------------------------------------------------------
__global__ __launch_bounds__(512)
void flash_attn_mfma(const short* __restrict__ q, const short* __restrict__ k,
                     const short* __restrict__ vt, const float* __restrict__ mask,
                     short* __restrict__ ctx) {
    const int bid = blockIdx.x;
    const int qt = bid / 48;               // 0..15
    const int bhid = bid % 48;             // 0..47; bid%8 == bhid%8 -> XCD-stable
    const int b = bhid / NH_, h = bhid % NH_;
    __shared__ __align__(16) short KsL[2][4096];   // [buf][64 s][128B] swz
    __shared__ __align__(16) short VtL[2][4096];   // [buf][64 d][128B] swz
    __shared__ __align__(16) uint2 PsP[128 * 16];  // [128 rows][16 uint2]
    const int tid = threadIdx.x;
    const int w = tid >> 6, l = tid & 63;
    const int l16 = l & 15, lg = l >> 4;

    const size_t bh = (size_t)(b * NH_ + h);
    bf16x8 qf0, qf1;
    {
        const size_t qr = (bh * S_ + (size_t)qt * 128 + w * 16 + l16) * HD_;
        qf0 = *(const bf16x8*)(q + qr + lg * 8);
        qf1 = *(const bf16x8*)(q + qr + 32 + lg * 8);
    }
    const size_t kbase  = bh * S_ * HD_;   // K  [s][d]
    const size_t vtbase = bh * HD_ * S_;   // Vt [d][s]

    bf16x8 ones;
    #pragma unroll
    for (int jj = 0; jj < 8; jj++) ones[jj] = (short)0x3F80;

    f32x4 oacc[4], lsum;
    #pragma unroll
    for (int i = 0; i < 4; i++) oacc[i][0] = oacc[i][1] = oacc[i][2] = oacc[i][3] = 0.f;
    lsum[0] = lsum[1] = lsum[2] = lsum[3] = 0.f;
    float m_reg = -3.0e38f;

    // staging: 512 threads x 16B = one full 8KB tile each for K and Vt
    const int srow = tid >> 3;             // 0..63
    const int sc0  = (tid & 7) * 16;       // byte col within 128B row
    const int wr0  = (srow << 7) + (sc0 ^ ((srow & 7) << 4));

    // P LDS geometry (uint2 units)
    const int prow = w * 16 + l16;         // this lane's P row (0..127)
    const int pu_base = prow * 16;

    bf16x8 nk, nv;
    #define LOADT(ct_) do {                                                        \
        nk = *(const bf16x8*)((const char*)(k  + kbase  + (size_t)((ct_) * 64 + srow) * HD_) + sc0); \
        nv = *(const bf16x8*)((const char*)(vt + vtbase + (size_t)srow * S_ + (ct_) * 64) + sc0);    \
    } while (0)
    #define WRITET(bu_) do {                                                       \
        *(bf16x8*)((char*)KsL[bu_] + wr0) = nk;                                    \
        *(bf16x8*)((char*)VtL[bu_] + wr0) = nv;                                    \
    } while (0)

    LOADT(0);
    WRITET(0);
    __syncthreads();

    int cbuf = 0;
    for (int ct = 0; ct < S_ / 64; ct++) {
        if (ct + 1 < S_ / 64) LOADT(ct + 1);   // issue early: hide under compute

        // ---- S^T = mfma(K, Q) with C initialized to the (log2-scaled) mask ----
        f32x4 sacc[4];
        #pragma unroll
        for (int n = 0; n < 4; n++) {
            float4 mk = *(const float4*)(mask + (size_t)b * S_ + ct * 64 + n * 16 + lg * 4);
            sacc[n][0] = mk.x; sacc[n][1] = mk.y; sacc[n][2] = mk.z; sacc[n][3] = mk.w;
        }
        __builtin_amdgcn_s_setprio(1);
        #pragma unroll
        for (int n = 0; n < 4; n++) {
            bf16x8 kb0 = *LDSRD(KsL[cbuf], n * 16 + l16, lg * 16);
            bf16x8 kb1 = *LDSRD(KsL[cbuf], n * 16 + l16, 64 + lg * 16);
            sacc[n] = __builtin_amdgcn_mfma_f32_16x16x32_bf16(kb0, qf0, sacc[n], 0, 0, 0);
            sacc[n] = __builtin_amdgcn_mfma_f32_16x16x32_bf16(kb1, qf1, sacc[n], 0, 0, 0);
        }
        __builtin_amdgcn_s_setprio(0);

        // ---- lane-local max for q-row l16 ----
        float x0 = fmaxf(fmaxf(sacc[0][0], sacc[0][1]), fmaxf(sacc[0][2], sacc[0][3]));
        float x1 = fmaxf(fmaxf(sacc[1][0], sacc[1][1]), fmaxf(sacc[1][2], sacc[1][3]));
        float x2 = fmaxf(fmaxf(sacc[2][0], sacc[2][1]), fmaxf(sacc[2][2], sacc[2][3]));
        float x3 = fmaxf(fmaxf(sacc[3][0], sacc[3][1]), fmaxf(sacc[3][2], sacc[3][3]));
        float pmax = fmaxf(fmaxf(x0, x1), fmaxf(x2, x3));
        pmax = fmaxf(pmax, __shfl_xor(pmax, 16));
        pmax = fmaxf(pmax, __shfl_xor(pmax, 32));

        // ---- defer-max rescale (T13) ----
        if (!__all(pmax - m_reg <= 8.f)) {
            const float mn = fmaxf(m_reg, pmax);
            const float corr = __builtin_amdgcn_exp2f(m_reg - mn);
            m_reg = mn;
            float corr4[4];
            #pragma unroll
            for (int r = 0; r < 4; r++) corr4[r] = __shfl(corr, lg * 4 + r);
            #pragma unroll
            for (int nd = 0; nd < 4; nd++)
                #pragma unroll
                for (int r = 0; r < 4; r++) oacc[nd][r] *= corr4[r];
            #pragma unroll
            for (int r = 0; r < 4; r++) lsum[r] *= corr4[r];
        }

        // ---- P = exp2(s - m): pack and store (same-typed uint2 LDS) ----
        #pragma unroll
        for (int n = 0; n < 4; n++) {
            uint2 pk;
            pk.x = cvt_pk_bf16(__builtin_amdgcn_exp2f(sacc[n][0] - m_reg),
                               __builtin_amdgcn_exp2f(sacc[n][1] - m_reg));
            pk.y = cvt_pk_bf16(__builtin_amdgcn_exp2f(sacc[n][2] - m_reg),
                               __builtin_amdgcn_exp2f(sacc[n][3] - m_reg));
            PsP[pu_base + ((4 * n + lg) ^ l16)] = pk;
        }
        // Compile-time fence (no elision/hoist across) ...
        asm volatile("" ::: "memory");
        // ... plus HARDWARE fence: drain the P ds_writes before any P ds_read
        // issues (LDS write->read of same bytes is not otherwise ordered).
        asm volatile("s_waitcnt lgkmcnt(0)" ::: "memory");
        __builtin_amdgcn_sched_barrier(0);

        // ---- rebuild PV A-fragments (same-typed uint2 reads) ----
        uint2 r0 = PsP[pu_base + ((2 * lg)     ^ l16)];
        uint2 r1 = PsP[pu_base + ((2 * lg + 1) ^ l16)];
        uint2 r2 = PsP[pu_base + ((8 + 2 * lg)     ^ l16)];
        uint2 r3 = PsP[pu_base + ((8 + 2 * lg + 1) ^ l16)];
        asm volatile("" ::: "memory");
        __builtin_amdgcn_sched_barrier(0);
        union U8 { unsigned u[4]; bf16x8 v; } A0, A1;
        A0.u[0] = r0.x; A0.u[1] = r0.y; A0.u[2] = r1.x; A0.u[3] = r1.y;
        A1.u[0] = r2.x; A1.u[1] = r2.y; A1.u[2] = r3.x; A1.u[3] = r3.y;
        bf16x8 pa0 = A0.v, pa1 = A1.v;

        // ---- write-early (R22): staged regs -> other buffer; the ds_writes
        //      drain under the PV MFMAs below instead of at the barrier ----
        if (ct + 1 < S_ / 64) WRITET(cbuf ^ 1);

        // ---- O += P V ; l += P 1 ----
        __builtin_amdgcn_s_setprio(1);
        lsum = __builtin_amdgcn_mfma_f32_16x16x32_bf16(pa0, ones, lsum, 0, 0, 0);
        lsum = __builtin_amdgcn_mfma_f32_16x16x32_bf16(pa1, ones, lsum, 0, 0, 0);
        #pragma unroll
        for (int nd = 0; nd < 4; nd++) {
            bf16x8 vb0 = *LDSRD(VtL[cbuf], nd * 16 + l16, lg * 16);
            bf16x8 vb1 = *LDSRD(VtL[cbuf], nd * 16 + l16, 64 + lg * 16);
            oacc[nd] = __builtin_amdgcn_mfma_f32_16x16x32_bf16(pa0, vb0, oacc[nd], 0, 0, 0);
            oacc[nd] = __builtin_amdgcn_mfma_f32_16x16x32_bf16(pa1, vb1, oacc[nd], 0, 0, 0);
        }
        __builtin_amdgcn_s_setprio(0);

        __syncthreads();   // publish next buffer / protect K,V reads
        cbuf ^= 1;
    }
    #undef LOADT
    #undef WRITET

    // ---- normalize + write ctx bf16 [M][H] (lsum already in O-layout) ----
    #pragma unroll
    for (int r = 0; r < 4; r++) {
        const float inv = 1.f / lsum[r];
        const size_t row = (size_t)(b * S_ + qt * 128 + w * 16 + lg * 4 + r);
        #pragma unroll
        for (int nd = 0; nd < 4; nd++)
            ctx[row * H_ + h * HD_ + nd * 16 + l16] = f2bf(oacc[nd][r] * inv);
    }
}

// ---------------------------------------------------------------------------
// LayerNorm over last dim (768). One block (256 thr) per row.
// ---------------------------------------------------------------------------
__global__ __launch_bounds__(256)
void layernorm_k(const float* __restrict__ hin, const float* __restrict__ g,
                 const float* __restrict__ beta, float* __restrict__ out) {
    const int row = blockIdx.x;
    const int tid = threadIdx.x;
    const float* x = hin + (size_t)row * H_;
    __shared__ float sm[4];

    float v0 = x[tid], v1 = x[tid + 256], v2 = x[tid + 512];
    float s = v0 + v1 + v2;
    #pragma unroll
    for (int o = 32; o > 0; o >>= 1) s += __shfl_xor(s, o);
    if ((tid & 63) == 0) sm[tid >> 6] = s;
    __syncthreads();
    float mu = (sm[0] + sm[1] + sm[2] + sm[3]) * (1.f / 768.f);

    float d0 = v0 - mu, d1 = v1 - mu, d2 = v2 - mu;
    float ss = d0*d0 + d1*d1 + d2*d2;
    #pragma unroll
    for (int o = 32; o > 0; o >>= 1) ss += __shfl_xor(ss, o);
    __syncthreads();
    if ((tid & 63) == 0) sm[tid >> 6] = ss;
    __syncthreads();
    float var = (sm[0] + sm[1] + sm[2] + sm[3]) * (1.f / 768.f);
    float sc = rsqrtf(var + 1e-12f);

    float* y = out + (size_t)row * H_;
    y[tid]       = d0 * sc * g[tid]       + beta[tid];
    y[tid + 256] = d1 * sc * g[tid + 256] + beta[tid + 256];
    y[tid + 512] = d2 * sc * g[tid + 512] + beta[tid + 512];
}

// ---------------------------------------------------------------------------
extern "C" void kernel_launch(void* const* d_in, const int* in_sizes, int n_in,
                              void* d_out, int out_size, void* d_ws, size_t ws_size,
                              hipStream_t stream) {
    const float* hs   = (const float*)d_in[0];
    const float* mask = (const float*)d_in[1];
    const float* Wq   = (const float*)d_in[2];
    const float* bq   = (const float*)d_in[3];
    const float* Wk   = (const float*)d_in[4];
    const float* bk   = (const float*)d_in[5];
    const float* Wv   = (const float*)d_in[6];
    const float* bv   = (const float*)d_in[7];
    const float* Wo   = (const float*)d_in[8];
    const float* bo   = (const float*)d_in[9];
    const float* ln_g = (const float*)d_in[10];
    const float* ln_b = (const float*)d_in[11];
    float* out = (float*)d_out;

    const size_t MH = (size_t)M_ * H_;
    const size_t HH = (size_t)H_ * H_;
    short* hsbf = (short*)d_ws;       // [M][768] bf16
    short* wqbf = hsbf + MH;          // [2304][768] consecutive Wq,Wk,Wv
    short* wkbf = wqbf + HH;
    short* wvbf = wkbf + HH;
    short* wobf = wvbf + HH;
    short* qbf  = wobf + HH;          // [b][h][s][d] bf16; q,k consecutive
    short* kbf  = qbf + MH;
    short* vtb  = kbf + MH;           // [b][h][d][s] (written by gemm_qkv)
    short* cbf  = vtb + MH;           // ctx bf16 [M][768]
    float* hb   = (float*)(cbf + MH); // fp32 [M][768]
    float* msk2 = hb + MH;            // mask * log2e (8192 fp32)

    cvt6<<<dim3(256, 6), 256, 0, stream>>>(hs, Wq, Wk, Wv, Wo, mask,
                                           hsbf, wqbf, wkbf, wvbf, wobf, msk2);

    gemm_qkv<<<dim3(1152), 256, 0, stream>>>(hsbf, wqbf, bq, bk, bv, qbf, vtb);

    flash_attn_mfma<<<dim3(768), 512, 0, stream>>>(qbf, kbf, vtb, msk2, cbf);

    gemm_out<<<dim3(384), 256, 0, stream>>>(cbf, wobf, bo, hs, hb);

    layernorm_k<<<M_, 256, 0, stream>>>(hb, ln_g, ln_b, out);
}